// Round 9
// baseline (634.719 us; speedup 1.0000x reference)
//
#include <hip/hip_runtime.h>
#include <math.h>

#define NB 32768
#define EPS_REC 1e-4f

// Inter-stage staging (static device globals: graph-capture safe).
__device__ float g_x2[NB * 256];  // stage-1 output: B x 16 x 16
__device__ float g_x3[NB * 16];   // stage-2 output: B x 4 x 4

// HISTORY (do not regress):
//  R5: dual-chain ILP -> occupancy halved, +22% time.
//  R6: __launch_bounds__(128,6) -> 85-reg cap -> spills (FETCH 407MB), +60%.
//  R8: 3 sweeps -> absmax 1.375 FAIL. 4 sweeps minimum (plateau 0.25-0.5).
//  R9/R10: two-sided, U in regs, 128-thr blocks: 641us, FETCH 23MB (clean).
//  R11: U in LDS: +10%. Shell (128-thr, valid-mask, (128,4)): ZERO scratch.
//  R12: ONE-SIDED Jacobi (col in regs, DPP gram, ds_bpermute tournament
//       movement): PASSED (absmax 0.5) but FETCH 492/WRITE 961MB.
//  R13-R18: swp[] removal / float4-SSA / waves_per_eu / LDS-pad / R11-shell
//       transplant / sched_barrier chunking: ALL byte-identical on traffic
//       (439/857MB) and VGPR(=64). Scratch also explains the 38% occupancy
//       cap (scratch allocation bounds resident waves) -> double cost.
//       ELIMINATION: the ONLY ingredient unique to all scratch builds and
//       absent from all clean builds is ds_bpermute carrying loop state.
//  R19 (this): one-sided kept (DPP gram, no U), but column movement done
//       the R0-proven way: rotated column STORED to permuted LDS slot
//       (5x ds_write_b128), wsync, LOADED back from own slot (5x
//       ds_read_b128). Zero ds_bpermute in the binary. Reuses ZB layout --
//       no extra LDS. Dummy-group write races store garbage that never
//       escapes (valid-masked output; DPP pairs confined to lanes 60-63).
__device__ __forceinline__ void wsync() {
  asm volatile("" ::: "memory");
  __builtin_amdgcn_wave_barrier();
  asm volatile("" ::: "memory");
}

// Swap values between adjacent lanes (lane ^ 1) via DPP quad_perm [1,0,3,2].
// Pairs (2k,2k+1) are even-aligned so they never cross a quad. VALU-pipe op.
__device__ __forceinline__ float dpp_swap1(float x) {
  int xi = __builtin_bit_cast(int, x);
  int yi = __builtin_amdgcn_update_dpp(xi, xi, 0xB1, 0xF, 0xF, true);
  return __builtin_bit_cast(float, yi);
}

// Tournament (circle-method): content of slot s moves to permf(s); with fixed
// pairing (2k,2k+1), every pair meets exactly once per N-1 rounds.
__host__ __device__ constexpr int permf(int s, int n) {
  return s == 0 ? 0
       : s == 2 ? 1
       : (s & 1) ? (s == n - 1 ? n - 2 : s + 2)
       : s - 2;
}

// Jacobi rotation (c,s) zeroing the (p,q) off-diagonal of the 2x2 Gram
// [[app,apq],[apq,aqq]]; G = [[c,s],[-s,c]].
__device__ __forceinline__ void rot_cs(float app, float aqq, float apq,
                                       float& c, float& s) {
  float dd = 0.5f * (app - aqq);
  float q2 = apq * apq;
  float hh = dd * dd + q2 + 1e-30f;
  float h = sqrtf(hh);
  float u = fabsf(dd) + h;
  float gi = rsqrtf(u * u + q2);
  c = u * gi;
  float smag = apq * gi;
  s = (dd >= 0.f) ? -smag : smag;
}

// Gram partial over one float4: d/n split into 2 accumulators each.
__device__ __forceinline__ void gram4(float4 a, float& d0, float& d1,
                                      float& n0, float& n1) {
  float s0 = dpp_swap1(a.x);
  d0 += a.x * s0;
  n0 += a.x * a.x;
  float s1 = dpp_swap1(a.y);
  d1 += a.y * s1;
  n1 += a.y * a.y;
  float s2 = dpp_swap1(a.z);
  d0 += a.z * s2;
  n0 += a.z * a.z;
  float s3 = dpp_swap1(a.w);
  d1 += a.w * s3;
  n1 += a.w * a.w;
}

// Rotate one float4 chunk: r = c*own + beta*partner (DPP reads pre-update
// partner values; result is a fresh value).
__device__ __forceinline__ float4 app4(float4 a, float c, float beta) {
  float4 r;
  r.x = fmaf(beta, dpp_swap1(a.x), c * a.x);
  r.y = fmaf(beta, dpp_swap1(a.y), c * a.y);
  r.z = fmaf(beta, dpp_swap1(a.z), c * a.z);
  r.w = fmaf(beta, dpp_swap1(a.w), c * a.w);
  return r;
}

// One one-sided round, 20 rows: gram (DPP) -> rot -> rotate chunks, store to
// permuted LDS column slot, wsync, load own slot back (tournament move).
__device__ __forceinline__ void round20(float4& a0, float4& a1, float4& a2,
                                        float4& a3, float4& a4, float4* SA4g,
                                        int sub, int wcol, bool isP) {
  float d0 = 0.f, d1 = 0.f, n0 = 0.f, n1 = 0.f;
  gram4(a0, d0, d1, n0, n1);
  gram4(a1, d0, d1, n0, n1);
  gram4(a2, d0, d1, n0, n1);
  gram4(a3, d0, d1, n0, n1);
  gram4(a4, d0, d1, n0, n1);
  float d = d0 + d1;
  float nOwn = n0 + n1;
  float nPrt = dpp_swap1(nOwn);
  float ne = isP ? nOwn : nPrt;  // canonical order: both pair lanes identical
  float no = isP ? nPrt : nOwn;
  float c, s;
  rot_cs(ne, no, d, c, s);
  float beta = isP ? -s : s;
  SA4g[0 * 20 + wcol] = app4(a0, c, beta);
  SA4g[1 * 20 + wcol] = app4(a1, c, beta);
  SA4g[2 * 20 + wcol] = app4(a2, c, beta);
  SA4g[3 * 20 + wcol] = app4(a3, c, beta);
  SA4g[4 * 20 + wcol] = app4(a4, c, beta);
  wsync();  // same-wave lockstep: all group writes complete in order
  a0 = SA4g[0 * 20 + sub];
  a1 = SA4g[1 * 20 + sub];
  a2 = SA4g[2 * 20 + sub];
  a3 = SA4g[3 * 20 + sub];
  a4 = SA4g[4 * 20 + sub];
  wsync();
}

// One one-sided round, 16 rows.
__device__ __forceinline__ void round16(float4& b0, float4& b1, float4& b2,
                                        float4& b3, float4* SA4g, int sub,
                                        int wcol, bool isP) {
  float d0 = 0.f, d1 = 0.f, n0 = 0.f, n1 = 0.f;
  gram4(b0, d0, d1, n0, n1);
  gram4(b1, d0, d1, n0, n1);
  gram4(b2, d0, d1, n0, n1);
  gram4(b3, d0, d1, n0, n1);
  float d = d0 + d1;
  float nOwn = n0 + n1;
  float nPrt = dpp_swap1(nOwn);
  float ne = isP ? nOwn : nPrt;
  float no = isP ? nPrt : nOwn;
  float c, s;
  rot_cs(ne, no, d, c, s);
  float beta = isP ? -s : s;
  SA4g[0 * 16 + wcol] = app4(b0, c, beta);
  SA4g[1 * 16 + wcol] = app4(b1, c, beta);
  SA4g[2 * 16 + wcol] = app4(b2, c, beta);
  SA4g[3 * 16 + wcol] = app4(b3, c, beta);
  wsync();
  b0 = SA4g[0 * 16 + sub];
  b1 = SA4g[1 * 16 + sub];
  b2 = SA4g[2 * 16 + sub];
  b3 = SA4g[3 * 16 + sub];
  wsync();
}

__device__ __forceinline__ float sq4(float4 a) {
  return (a.x * a.x + a.y * a.y) + (a.z * a.z + a.w * a.w);
}

// Stage 1: X1 = w1^T X w1 (19 padded to 20), one-sided Jacobi, then
// X2 = Y^T Lamc Y with Y[j] = w2^T u_j. 3 matrices per wave (lanes 60..63
// -> shared dummy slot 6), 128-thread blocks = 6 matrices. R11 shell.
__global__ __launch_bounds__(128, 4) void spd_stage1(
    const float* __restrict__ x, const float* __restrict__ w1,
    const float* __restrict__ w2) {
  __shared__ float4 ZB[7 * 100];  // Z staging / movement buffer / Y rows
  __shared__ float SL[7 * 20];
  int tid = threadIdx.x;
  int wid = tid >> 6;
  int lane = tid & 63;
  int gl = lane / 20;  // 0..3 (3 = idle lanes 60..63)
  int sub = lane - gl * 20;
  bool lane_ok = (gl < 3);
  int g = lane_ok ? (wid * 3 + gl) : 6;
  int b = blockIdx.x * 6 + g;
  bool valid = lane_ok && (b < NB);
  int bm = valid ? b : 0;
  float4* ZB4 = ZB + g * 100;
  float* ZBf = (float*)ZB4;
  float* SLg = SL + g * 20;

  // ---- bilinear: Z = w1^T X (col sub), then X1 col sub = (Z w1) col ----
  const float* xb = x + bm * 361;
  float cx[19];
#pragma unroll
  for (int i = 0; i < 19; ++i) cx[i] = (sub < 19) ? xb[i * 19 + sub] : 0.f;
  float z[20];
  z[19] = 0.f;
#pragma unroll
  for (int i = 0; i < 19; ++i) {
    float acc = 0.f;
#pragma unroll
    for (int r = 0; r < 19; ++r) acc += w1[r * 19 + i] * cx[r];
    z[i] = acc;
  }
#pragma unroll
  for (int t = 0; t < 5; ++t)
    ZB4[t * 20 + sub] =
        make_float4(z[4 * t], z[4 * t + 1], z[4 * t + 2], z[4 * t + 3]);
  wsync();
  float wj[19];
#pragma unroll
  for (int r = 0; r < 19; ++r) wj[r] = (sub < 19) ? w1[r * 19 + sub] : 0.f;
  float4 a0 = make_float4(0.f, 0.f, 0.f, 0.f);
  float4 a1 = a0, a2 = a0, a3 = a0, a4 = a0;
#pragma unroll
  for (int r = 0; r < 19; ++r) {
    float wr = wj[r];
    float4 zc;
    zc = ZB4[0 * 20 + r];
    a0.x += zc.x * wr; a0.y += zc.y * wr; a0.z += zc.z * wr; a0.w += zc.w * wr;
    zc = ZB4[1 * 20 + r];
    a1.x += zc.x * wr; a1.y += zc.y * wr; a1.z += zc.z * wr; a1.w += zc.w * wr;
    zc = ZB4[2 * 20 + r];
    a2.x += zc.x * wr; a2.y += zc.y * wr; a2.z += zc.z * wr; a2.w += zc.w * wr;
    zc = ZB4[3 * 20 + r];
    a3.x += zc.x * wr; a3.y += zc.y * wr; a3.z += zc.z * wr; a3.w += zc.w * wr;
    zc = ZB4[4 * 20 + r];
    a4.x += zc.x * wr; a4.y += zc.y * wr; a4.z += zc.z * wr; a4.w += zc.w * wr;
  }
  // a0..a4 = X1 column sub; pad column 19 is exactly 0 (stays 0: d=0 => s=0).
  // Dummy lanes hold garbage after races: confined to group 6, never output.
  wsync();  // Z reads done before the round loop overwrites ZB

  const int wcol = permf(sub, 20);
  const bool isP = !(sub & 1);
#pragma unroll 1
  for (int it = 0; it < 76; ++it)  // 4 sweeps (validated minimum)
    round20(a0, a1, a2, a3, a4, ZB4, sub, wcol, isP);

  // lambda_j = ||col||, u_j = col/||col|| (guarded for the zero pad column)
  float nOwn = ((sq4(a0) + sq4(a1)) + (sq4(a2) + sq4(a3))) + sq4(a4);
  float lamc = fmaxf(sqrtf(nOwn), EPS_REC);
  float nrm = nOwn + 1e-30f;
  float inv = rsqrtf(nrm);
  inv = inv * (1.5f - 0.5f * nrm * inv * inv);  // 1 NR step
  // Unpack to a short-lived static array for the tail (R11-proven clean).
  float cv[20];
  cv[0] = a0.x; cv[1] = a0.y; cv[2] = a0.z; cv[3] = a0.w;
  cv[4] = a1.x; cv[5] = a1.y; cv[6] = a1.z; cv[7] = a1.w;
  cv[8] = a2.x; cv[9] = a2.y; cv[10] = a2.z; cv[11] = a2.w;
  cv[12] = a3.x; cv[13] = a3.y; cv[14] = a3.z; cv[15] = a3.w;
  cv[16] = a4.x; cv[17] = a4.y; cv[18] = a4.z; cv[19] = a4.w;
  // y[k] = sum_{i<19} w2[i][k] * u_j[i]   (in-lane; w2 uniform -> scalar lds)
  float y[16];
#pragma unroll
  for (int k = 0; k < 16; ++k) y[k] = 0.f;
#pragma unroll
  for (int i = 0; i < 19; ++i) {
    float ui = cv[i];
#pragma unroll
    for (int k = 0; k < 16; ++k) y[k] += w2[i * 16 + k] * ui;
  }
#pragma unroll
  for (int k = 0; k < 16; ++k) y[k] *= inv;
  wsync();  // movement buffer dead; reuse ZB for Y rows
  SLg[sub] = lamc;
#pragma unroll
  for (int t = 0; t < 4; ++t)
    ZB4[sub * 4 + t] =
        make_float4(y[4 * t], y[4 * t + 1], y[4 * t + 2], y[4 * t + 3]);
  wsync();
  // X2[i][sub] = sum_j lamc_j Y[j][i] Y[j][sub]
  if (valid && sub < 16) {
    float acc[16];
#pragma unroll
    for (int i = 0; i < 16; ++i) acc[i] = 0.f;
#pragma unroll
    for (int r = 0; r < 20; ++r) {
      float pr = SLg[r] * ZBf[r * 16 + sub];
#pragma unroll
      for (int t = 0; t < 4; ++t) {
        float4 yr = ZB4[r * 4 + t];  // Y row r, cols 4t..4t+3 (broadcast)
        acc[4 * t + 0] += pr * yr.x;
        acc[4 * t + 1] += pr * yr.y;
        acc[4 * t + 2] += pr * yr.z;
        acc[4 * t + 3] += pr * yr.w;
      }
    }
    float* outb = g_x2 + b * 256;
#pragma unroll
    for (int i = 0; i < 16; ++i) outb[i * 16 + sub] = acc[i];
  }
}

// Stage 2: one-sided Jacobi on 16x16, X3 = Y3^T Lamc Y3 with Y3[j]=w3^T u_j.
// 4 matrices per wave, 128-thread blocks = 8 matrices, all lanes active.
__global__ __launch_bounds__(128, 4) void spd_stage2(
    const float* __restrict__ w3) {
  __shared__ float4 SB[8 * 64];  // movement buffer
  __shared__ float4 Y3L[8 * 16];
  __shared__ float SL2[8 * 16];
  int tid = threadIdx.x;
  int wid = tid >> 6;
  int lane = tid & 63;
  int gl = lane >> 4;
  int sub = lane & 15;
  int g = wid * 4 + gl;
  int b = blockIdx.x * 8 + g;
  float4* SB4 = SB + g * 64;
  float* Y3f = (float*)(Y3L + g * 16);
  float* SLg = SL2 + g * 16;

  const float* xb = g_x2 + b * 256;
  float4 b0 = make_float4(xb[0 * 16 + sub], xb[1 * 16 + sub], xb[2 * 16 + sub],
                          xb[3 * 16 + sub]);
  float4 b1 = make_float4(xb[4 * 16 + sub], xb[5 * 16 + sub], xb[6 * 16 + sub],
                          xb[7 * 16 + sub]);
  float4 b2 = make_float4(xb[8 * 16 + sub], xb[9 * 16 + sub],
                          xb[10 * 16 + sub], xb[11 * 16 + sub]);
  float4 b3 = make_float4(xb[12 * 16 + sub], xb[13 * 16 + sub],
                          xb[14 * 16 + sub], xb[15 * 16 + sub]);

  const int wcol = permf(sub, 16);
  const bool isP = !(sub & 1);
#pragma unroll 1
  for (int it = 0; it < 60; ++it)  // 4 sweeps
    round16(b0, b1, b2, b3, SB4, sub, wcol, isP);

  float nOwn = (sq4(b0) + sq4(b1)) + (sq4(b2) + sq4(b3));
  float lamc = fmaxf(sqrtf(nOwn), EPS_REC);
  float nrm = nOwn + 1e-30f;
  float inv = rsqrtf(nrm);
  inv = inv * (1.5f - 0.5f * nrm * inv * inv);
  float cv[16];
  cv[0] = b0.x; cv[1] = b0.y; cv[2] = b0.z; cv[3] = b0.w;
  cv[4] = b1.x; cv[5] = b1.y; cv[6] = b1.z; cv[7] = b1.w;
  cv[8] = b2.x; cv[9] = b2.y; cv[10] = b2.z; cv[11] = b2.w;
  cv[12] = b3.x; cv[13] = b3.y; cv[14] = b3.z; cv[15] = b3.w;
  float y3[4] = {0.f, 0.f, 0.f, 0.f};
#pragma unroll
  for (int i = 0; i < 16; ++i) {
    float ui = cv[i];
#pragma unroll
    for (int j = 0; j < 4; ++j) y3[j] += w3[i * 4 + j] * ui;
  }
#pragma unroll
  for (int j = 0; j < 4; ++j) y3[j] *= inv;
  SLg[sub] = lamc;
  ((float4*)Y3f)[sub] = make_float4(y3[0], y3[1], y3[2], y3[3]);
  wsync();
  int ii = sub >> 2, jj = sub & 3;
  float acc = 0.f;
#pragma unroll
  for (int r = 0; r < 16; ++r)
    acc += SLg[r] * Y3f[r * 4 + ii] * Y3f[r * 4 + jj];
  g_x3[b * 16 + sub] = acc;
}

// Stage 3: per-thread 4x4 LogEig in registers, FC(16->2), log_softmax.
__global__ __launch_bounds__(256) void spd_stage3(const float* __restrict__ fcw,
                                                  float* __restrict__ out) {
  int b = blockIdx.x * 256 + threadIdx.x;
  const float* xb = g_x3 + b * 16;
  float a[4][4];
#pragma unroll
  for (int i = 0; i < 4; ++i)
#pragma unroll
    for (int j = 0; j < 4; ++j) a[i][j] = xb[i * 4 + j];
  float vv[4][4];
#pragma unroll
  for (int i = 0; i < 4; ++i)
#pragma unroll
    for (int j = 0; j < 4; ++j) vv[i][j] = (i == j) ? 1.f : 0.f;

  constexpr int P4[6] = {0, 0, 0, 1, 1, 2};
  constexpr int Q4[6] = {1, 2, 3, 2, 3, 3};
  for (int sw = 0; sw < 6; ++sw) {
#pragma unroll
    for (int e = 0; e < 6; ++e) {
      const int p = P4[e], q = Q4[e];
      float c, s;
      rot_cs(a[p][p], a[q][q], a[p][q], c, s);
#pragma unroll
      for (int j = 0; j < 4; ++j) {
        float xx = a[p][j], yy = a[q][j];
        a[p][j] = c * xx - s * yy;
        a[q][j] = s * xx + c * yy;
      }
#pragma unroll
      for (int i = 0; i < 4; ++i) {
        float xx = a[i][p], yy = a[i][q];
        a[i][p] = c * xx - s * yy;
        a[i][q] = s * xx + c * yy;
      }
#pragma unroll
      for (int i = 0; i < 4; ++i) {
        float xx = vv[i][p], yy = vv[i][q];
        vv[i][p] = c * xx - s * yy;
        vv[i][q] = s * xx + c * yy;
      }
    }
  }
  float ll[4];
#pragma unroll
  for (int r = 0; r < 4; ++r) ll[r] = logf(fmaxf(a[r][r], 1e-12f));
  float feat[16];
#pragma unroll
  for (int i = 0; i < 4; ++i)
#pragma unroll
    for (int j = 0; j < 4; ++j) {
      float acc = 0.f;
#pragma unroll
      for (int r = 0; r < 4; ++r) acc += ll[r] * vv[i][r] * vv[j][r];
      feat[i * 4 + j] = acc;
    }
  float z0 = 0.f, z1 = 0.f;
#pragma unroll
  for (int k = 0; k < 16; ++k) {
    z0 += feat[k] * fcw[2 * k + 0];
    z1 += feat[k] * fcw[2 * k + 1];
  }
  float m = fmaxf(z0, z1);
  float lse = logf(expf(z0 - m) + expf(z1 - m));
  out[b * 2 + 0] = z0 - m - lse;
  out[b * 2 + 1] = z1 - m - lse;
#pragma unroll
  for (int k = 0; k < 16; ++k) out[2 * NB + b * 16 + k] = feat[k];
}

extern "C" void kernel_launch(void* const* d_in, const int* in_sizes, int n_in,
                              void* d_out, int out_size, void* d_ws,
                              size_t ws_size, hipStream_t stream) {
  (void)in_sizes;
  (void)n_in;
  (void)out_size;
  (void)d_ws;
  (void)ws_size;
  const float* x = (const float*)d_in[0];
  const float* w1 = (const float*)d_in[1];
  const float* w2 = (const float*)d_in[2];
  const float* w3 = (const float*)d_in[3];
  const float* fcw = (const float*)d_in[4];
  float* out = (float*)d_out;

  spd_stage1<<<(NB + 5) / 6, 128, 0, stream>>>(x, w1, w2);
  spd_stage2<<<NB / 8, 128, 0, stream>>>(w3);
  spd_stage3<<<NB / 256, 256, 0, stream>>>(fcw, out);
}

// Round 10
// 401.886 us; speedup vs baseline: 1.5793x; 1.5793x over previous
//
#include <hip/hip_runtime.h>
#include <math.h>

#define NB 32768
#define EPS_REC 1e-4f

// Inter-stage staging (static device globals: graph-capture safe).
__device__ float g_x2[NB * 256];  // stage-1 output: B x 16 x 16
__device__ float g_x3[NB * 16];   // stage-2 output: B x 4 x 4

// HISTORY (do not regress):
//  R5: dual-chain ILP -> occupancy halved, +22%. R6: reg-cap spills, +60%.
//  R8: 3 sweeps FAIL (absmax 1.375); 4 sweeps minimum (plateau 0.25-0.5).
//  R9/R10: two-sided, U in regs: 641us, FETCH 23MB. Round shape: state
//       HOMED IN LDS, chunks loaded/stored per round, intra-round arrays
//       only; loop-carried ur/un -> AGPR shuttle (NOT scratch). CLEAN.
//  R11: U in LDS: +10% (more b128). Still clean.
//  R12-R19: one-sided Jacobi with REGISTER-carried column state across the
//       pragma-unroll-1 back-edge. PASSED (absmax 0.5) but 430-490MB FETCH /
//       850-960MB WRITE scratch traffic, VGPR pinned at 64, occupancy 38%.
//       Falsified one by one: swp[] array (R13), array-vs-SSA form (R14),
//       waves_per_eu (R15), LDS-pad occupancy coupling (R16), shell/early-
//       return (R17), sched_barrier regions (R18), ds_bpermute (R19 -- LDS
//       movement instead, traffic unchanged). Only surviving delta vs clean
//       builds: LOOP-CARRIED REGISTER STATE ACROSS THE BACK-EDGE.
//  R20 (this): LDS-homed columns, R0's exact proven round shape: load own
//       column (5x b128) -> gram via DPP -> rot -> rotate+store to permuted
//       slot (5x b128) -> wsync. NOTHING register-carried across the
//       back-edge. Same LDS op count as R19 (movement round-trip = home).
__device__ __forceinline__ void wsync() {
  asm volatile("" ::: "memory");
  __builtin_amdgcn_wave_barrier();
  asm volatile("" ::: "memory");
}

// Swap values between adjacent lanes (lane ^ 1) via DPP quad_perm [1,0,3,2].
// Pairs (2k,2k+1) are even-aligned so they never cross a quad. VALU-pipe op.
__device__ __forceinline__ float dpp_swap1(float x) {
  int xi = __builtin_bit_cast(int, x);
  int yi = __builtin_amdgcn_update_dpp(xi, xi, 0xB1, 0xF, 0xF, true);
  return __builtin_bit_cast(float, yi);
}

// Tournament (circle-method): content of slot s moves to permf(s); with fixed
// pairing (2k,2k+1), every pair meets exactly once per N-1 rounds.
__host__ __device__ constexpr int permf(int s, int n) {
  return s == 0 ? 0
       : s == 2 ? 1
       : (s & 1) ? (s == n - 1 ? n - 2 : s + 2)
       : s - 2;
}

// Jacobi rotation (c,s) zeroing the (p,q) off-diagonal of the 2x2 Gram
// [[app,apq],[apq,aqq]]; G = [[c,s],[-s,c]].
__device__ __forceinline__ void rot_cs(float app, float aqq, float apq,
                                       float& c, float& s) {
  float dd = 0.5f * (app - aqq);
  float q2 = apq * apq;
  float hh = dd * dd + q2 + 1e-30f;
  float h = sqrtf(hh);
  float u = fabsf(dd) + h;
  float gi = rsqrtf(u * u + q2);
  c = u * gi;
  float smag = apq * gi;
  s = (dd >= 0.f) ? -smag : smag;
}

// Gram partial over one float4: d/n split into 2 accumulators each.
__device__ __forceinline__ void gram4(float4 a, float& d0, float& d1,
                                      float& n0, float& n1) {
  float s0 = dpp_swap1(a.x);
  d0 += a.x * s0;
  n0 += a.x * a.x;
  float s1 = dpp_swap1(a.y);
  d1 += a.y * s1;
  n1 += a.y * a.y;
  float s2 = dpp_swap1(a.z);
  d0 += a.z * s2;
  n0 += a.z * a.z;
  float s3 = dpp_swap1(a.w);
  d1 += a.w * s3;
  n1 += a.w * a.w;
}

// Rotate one float4 chunk: r = c*own + beta*partner (DPP reads pre-update
// register values loaded at round start; result is a fresh value).
__device__ __forceinline__ float4 app4(float4 a, float c, float beta) {
  float4 r;
  r.x = fmaf(beta, dpp_swap1(a.x), c * a.x);
  r.y = fmaf(beta, dpp_swap1(a.y), c * a.y);
  r.z = fmaf(beta, dpp_swap1(a.z), c * a.z);
  r.w = fmaf(beta, dpp_swap1(a.w), c * a.w);
  return r;
}

// One one-sided round, 20 rows, LDS-homed (R0 shape): load own column,
// gram via DPP, rotate, store to permuted slot. No loop-carried registers.
__device__ __forceinline__ void round20L(float4* SA4g, int sub, int wcol,
                                         bool isP) {
  float4 a0 = SA4g[0 * 20 + sub];
  float4 a1 = SA4g[1 * 20 + sub];
  float4 a2 = SA4g[2 * 20 + sub];
  float4 a3 = SA4g[3 * 20 + sub];
  float4 a4 = SA4g[4 * 20 + sub];
  float d0 = 0.f, d1 = 0.f, n0 = 0.f, n1 = 0.f;
  gram4(a0, d0, d1, n0, n1);
  gram4(a1, d0, d1, n0, n1);
  gram4(a2, d0, d1, n0, n1);
  gram4(a3, d0, d1, n0, n1);
  gram4(a4, d0, d1, n0, n1);
  float d = d0 + d1;
  float nOwn = n0 + n1;
  float nPrt = dpp_swap1(nOwn);
  float ne = isP ? nOwn : nPrt;  // canonical order: both pair lanes identical
  float no = isP ? nPrt : nOwn;
  float c, s;
  rot_cs(ne, no, d, c, s);
  float beta = isP ? -s : s;
  wsync();  // all own-slot reads precede any overwrite (same-wave lockstep)
  SA4g[0 * 20 + wcol] = app4(a0, c, beta);
  SA4g[1 * 20 + wcol] = app4(a1, c, beta);
  SA4g[2 * 20 + wcol] = app4(a2, c, beta);
  SA4g[3 * 20 + wcol] = app4(a3, c, beta);
  SA4g[4 * 20 + wcol] = app4(a4, c, beta);
  wsync();  // stores complete before next round's loads
}

// One one-sided round, 16 rows, LDS-homed.
__device__ __forceinline__ void round16L(float4* SB4, int sub, int wcol,
                                         bool isP) {
  float4 b0 = SB4[0 * 16 + sub];
  float4 b1 = SB4[1 * 16 + sub];
  float4 b2 = SB4[2 * 16 + sub];
  float4 b3 = SB4[3 * 16 + sub];
  float d0 = 0.f, d1 = 0.f, n0 = 0.f, n1 = 0.f;
  gram4(b0, d0, d1, n0, n1);
  gram4(b1, d0, d1, n0, n1);
  gram4(b2, d0, d1, n0, n1);
  gram4(b3, d0, d1, n0, n1);
  float d = d0 + d1;
  float nOwn = n0 + n1;
  float nPrt = dpp_swap1(nOwn);
  float ne = isP ? nOwn : nPrt;
  float no = isP ? nPrt : nOwn;
  float c, s;
  rot_cs(ne, no, d, c, s);
  float beta = isP ? -s : s;
  wsync();
  SB4[0 * 16 + wcol] = app4(b0, c, beta);
  SB4[1 * 16 + wcol] = app4(b1, c, beta);
  SB4[2 * 16 + wcol] = app4(b2, c, beta);
  SB4[3 * 16 + wcol] = app4(b3, c, beta);
  wsync();
}

__device__ __forceinline__ float sq4(float4 a) {
  return (a.x * a.x + a.y * a.y) + (a.z * a.z + a.w * a.w);
}

// Stage 1: X1 = w1^T X w1 (19 padded to 20), one-sided Jacobi (LDS-homed),
// then X2 = Y^T Lamc Y with Y[j] = w2^T u_j. Final slot permutation is
// irrelevant: X2 sums over eigenpairs symmetrically. 3 matrices per wave
// (lanes 60..63 -> shared dummy slot 6), 128-thread blocks. R11 shell.
__global__ __launch_bounds__(128, 4) void spd_stage1(
    const float* __restrict__ x, const float* __restrict__ w1,
    const float* __restrict__ w2) {
  __shared__ float4 ZB[7 * 100];  // Z staging / column home / Y rows
  __shared__ float SL[7 * 20];
  int tid = threadIdx.x;
  int wid = tid >> 6;
  int lane = tid & 63;
  int gl = lane / 20;  // 0..3 (3 = idle lanes 60..63)
  int sub = lane - gl * 20;
  bool lane_ok = (gl < 3);
  int g = lane_ok ? (wid * 3 + gl) : 6;
  int b = blockIdx.x * 6 + g;
  bool valid = lane_ok && (b < NB);
  int bm = valid ? b : 0;
  float4* ZB4 = ZB + g * 100;
  float* ZBf = (float*)ZB4;
  float* SLg = SL + g * 20;

  // ---- bilinear: Z = w1^T X (col sub), then X1 col sub = (Z w1) col ----
  const float* xb = x + bm * 361;
  float cx[19];
#pragma unroll
  for (int i = 0; i < 19; ++i) cx[i] = (sub < 19) ? xb[i * 19 + sub] : 0.f;
  float z[20];
  z[19] = 0.f;
#pragma unroll
  for (int i = 0; i < 19; ++i) {
    float acc = 0.f;
#pragma unroll
    for (int r = 0; r < 19; ++r) acc += w1[r * 19 + i] * cx[r];
    z[i] = acc;
  }
#pragma unroll
  for (int t = 0; t < 5; ++t)
    ZB4[t * 20 + sub] =
        make_float4(z[4 * t], z[4 * t + 1], z[4 * t + 2], z[4 * t + 3]);
  wsync();
  float wj[19];
#pragma unroll
  for (int r = 0; r < 19; ++r) wj[r] = (sub < 19) ? w1[r * 19 + sub] : 0.f;
  float a1c[20];
#pragma unroll
  for (int i = 0; i < 20; ++i) a1c[i] = 0.f;
#pragma unroll
  for (int r = 0; r < 19; ++r) {
    float wr = wj[r];
#pragma unroll
    for (int t = 0; t < 5; ++t) {
      float4 zc = ZB4[t * 20 + r];  // Z rows 4t..4t+3, col r (broadcast)
      a1c[4 * t + 0] += zc.x * wr;
      a1c[4 * t + 1] += zc.y * wr;
      a1c[4 * t + 2] += zc.z * wr;
      a1c[4 * t + 3] += zc.w * wr;
    }
  }
  wsync();  // Z reads done; ZB becomes the column home
  // Store X1 column sub into home. Pad column 19 is exactly 0 (d=0 => s=0).
  // Dummy group 6 races -> garbage, confined to slot 6, never output.
#pragma unroll
  for (int t = 0; t < 5; ++t)
    ZB4[t * 20 + sub] = make_float4(a1c[4 * t], a1c[4 * t + 1],
                                    a1c[4 * t + 2], a1c[4 * t + 3]);
  wsync();

  const int wcol = permf(sub, 20);
  const bool isP = !(sub & 1);
#pragma unroll 1
  for (int it = 0; it < 76; ++it)  // 4 sweeps (validated minimum)
    round20L(ZB4, sub, wcol, isP);

  // Load final column; lambda_j = ||col||, u_j = col/||col||.
  float cv[20];
#pragma unroll
  for (int t = 0; t < 5; ++t) {
    float4 a = ZB4[t * 20 + sub];
    cv[4 * t + 0] = a.x;
    cv[4 * t + 1] = a.y;
    cv[4 * t + 2] = a.z;
    cv[4 * t + 3] = a.w;
  }
  float m0 = 0.f, m1 = 0.f;
#pragma unroll
  for (int i = 0; i < 20; i += 2) {
    m0 += cv[i] * cv[i];
    m1 += cv[i + 1] * cv[i + 1];
  }
  float nOwn = m0 + m1;
  float lamc = fmaxf(sqrtf(nOwn), EPS_REC);
  float nrm = nOwn + 1e-30f;
  float inv = rsqrtf(nrm);
  inv = inv * (1.5f - 0.5f * nrm * inv * inv);  // 1 NR step
  // y[k] = sum_{i<19} w2[i][k] * u_j[i]   (in-lane; w2 uniform -> scalar lds)
  float y[16];
#pragma unroll
  for (int k = 0; k < 16; ++k) y[k] = 0.f;
#pragma unroll
  for (int i = 0; i < 19; ++i) {
    float ui = cv[i];
#pragma unroll
    for (int k = 0; k < 16; ++k) y[k] += w2[i * 16 + k] * ui;
  }
#pragma unroll
  for (int k = 0; k < 16; ++k) y[k] *= inv;
  wsync();  // column home dead; reuse ZB for Y rows
  SLg[sub] = lamc;
#pragma unroll
  for (int t = 0; t < 4; ++t)
    ZB4[sub * 4 + t] =
        make_float4(y[4 * t], y[4 * t + 1], y[4 * t + 2], y[4 * t + 3]);
  wsync();
  // X2[i][sub] = sum_j lamc_j Y[j][i] Y[j][sub]  (order-independent sum)
  if (valid && sub < 16) {
    float acc[16];
#pragma unroll
    for (int i = 0; i < 16; ++i) acc[i] = 0.f;
#pragma unroll
    for (int r = 0; r < 20; ++r) {
      float pr = SLg[r] * ZBf[r * 16 + sub];
#pragma unroll
      for (int t = 0; t < 4; ++t) {
        float4 yr = ZB4[r * 4 + t];  // Y row r, cols 4t..4t+3 (broadcast)
        acc[4 * t + 0] += pr * yr.x;
        acc[4 * t + 1] += pr * yr.y;
        acc[4 * t + 2] += pr * yr.z;
        acc[4 * t + 3] += pr * yr.w;
      }
    }
    float* outb = g_x2 + b * 256;
#pragma unroll
    for (int i = 0; i < 16; ++i) outb[i * 16 + sub] = acc[i];
  }
}

// Stage 2: one-sided Jacobi on 16x16 (LDS-homed), X3 = Y3^T Lamc Y3 with
// Y3[j]=w3^T u_j. 4 matrices per wave, 128-thread blocks, all lanes active.
__global__ __launch_bounds__(128, 4) void spd_stage2(
    const float* __restrict__ w3) {
  __shared__ float4 SB[8 * 64];  // column home
  __shared__ float4 Y3L[8 * 16];
  __shared__ float SL2[8 * 16];
  int tid = threadIdx.x;
  int wid = tid >> 6;
  int lane = tid & 63;
  int gl = lane >> 4;
  int sub = lane & 15;
  int g = wid * 4 + gl;
  int b = blockIdx.x * 8 + g;
  float4* SB4 = SB + g * 64;
  float* Y3f = (float*)(Y3L + g * 16);
  float* SLg = SL2 + g * 16;

  const float* xb = g_x2 + b * 256;
  float ca[16];
#pragma unroll
  for (int i = 0; i < 16; ++i) ca[i] = xb[i * 16 + sub];
#pragma unroll
  for (int t = 0; t < 4; ++t)
    SB4[t * 16 + sub] =
        make_float4(ca[4 * t], ca[4 * t + 1], ca[4 * t + 2], ca[4 * t + 3]);
  wsync();

  const int wcol = permf(sub, 16);
  const bool isP = !(sub & 1);
#pragma unroll 1
  for (int it = 0; it < 60; ++it)  // 4 sweeps
    round16L(SB4, sub, wcol, isP);

  float cv[16];
#pragma unroll
  for (int t = 0; t < 4; ++t) {
    float4 a = SB4[t * 16 + sub];
    cv[4 * t + 0] = a.x;
    cv[4 * t + 1] = a.y;
    cv[4 * t + 2] = a.z;
    cv[4 * t + 3] = a.w;
  }
  float m0 = 0.f, m1 = 0.f;
#pragma unroll
  for (int i = 0; i < 16; i += 2) {
    m0 += cv[i] * cv[i];
    m1 += cv[i + 1] * cv[i + 1];
  }
  float nOwn = m0 + m1;
  float lamc = fmaxf(sqrtf(nOwn), EPS_REC);
  float nrm = nOwn + 1e-30f;
  float inv = rsqrtf(nrm);
  inv = inv * (1.5f - 0.5f * nrm * inv * inv);
  float y3[4] = {0.f, 0.f, 0.f, 0.f};
#pragma unroll
  for (int i = 0; i < 16; ++i) {
    float ui = cv[i];
#pragma unroll
    for (int j = 0; j < 4; ++j) y3[j] += w3[i * 4 + j] * ui;
  }
#pragma unroll
  for (int j = 0; j < 4; ++j) y3[j] *= inv;
  SLg[sub] = lamc;
  ((float4*)Y3f)[sub] = make_float4(y3[0], y3[1], y3[2], y3[3]);
  wsync();
  int ii = sub >> 2, jj = sub & 3;
  float acc = 0.f;
#pragma unroll
  for (int r = 0; r < 16; ++r)
    acc += SLg[r] * Y3f[r * 4 + ii] * Y3f[r * 4 + jj];
  g_x3[b * 16 + sub] = acc;
}

// Stage 3: per-thread 4x4 LogEig in registers, FC(16->2), log_softmax.
__global__ __launch_bounds__(256) void spd_stage3(const float* __restrict__ fcw,
                                                  float* __restrict__ out) {
  int b = blockIdx.x * 256 + threadIdx.x;
  const float* xb = g_x3 + b * 16;
  float a[4][4];
#pragma unroll
  for (int i = 0; i < 4; ++i)
#pragma unroll
    for (int j = 0; j < 4; ++j) a[i][j] = xb[i * 4 + j];
  float vv[4][4];
#pragma unroll
  for (int i = 0; i < 4; ++i)
#pragma unroll
    for (int j = 0; j < 4; ++j) vv[i][j] = (i == j) ? 1.f : 0.f;

  constexpr int P4[6] = {0, 0, 0, 1, 1, 2};
  constexpr int Q4[6] = {1, 2, 3, 2, 3, 3};
  for (int sw = 0; sw < 6; ++sw) {
#pragma unroll
    for (int e = 0; e < 6; ++e) {
      const int p = P4[e], q = Q4[e];
      float c, s;
      rot_cs(a[p][p], a[q][q], a[p][q], c, s);
#pragma unroll
      for (int j = 0; j < 4; ++j) {
        float xx = a[p][j], yy = a[q][j];
        a[p][j] = c * xx - s * yy;
        a[q][j] = s * xx + c * yy;
      }
#pragma unroll
      for (int i = 0; i < 4; ++i) {
        float xx = a[i][p], yy = a[i][q];
        a[i][p] = c * xx - s * yy;
        a[i][q] = s * xx + c * yy;
      }
#pragma unroll
      for (int i = 0; i < 4; ++i) {
        float xx = vv[i][p], yy = vv[i][q];
        vv[i][p] = c * xx - s * yy;
        vv[i][q] = s * xx + c * yy;
      }
    }
  }
  float ll[4];
#pragma unroll
  for (int r = 0; r < 4; ++r) ll[r] = logf(fmaxf(a[r][r], 1e-12f));
  float feat[16];
#pragma unroll
  for (int i = 0; i < 4; ++i)
#pragma unroll
    for (int j = 0; j < 4; ++j) {
      float acc = 0.f;
#pragma unroll
      for (int r = 0; r < 4; ++r) acc += ll[r] * vv[i][r] * vv[j][r];
      feat[i * 4 + j] = acc;
    }
  float z0 = 0.f, z1 = 0.f;
#pragma unroll
  for (int k = 0; k < 16; ++k) {
    z0 += feat[k] * fcw[2 * k + 0];
    z1 += feat[k] * fcw[2 * k + 1];
  }
  float m = fmaxf(z0, z1);
  float lse = logf(expf(z0 - m) + expf(z1 - m));
  out[b * 2 + 0] = z0 - m - lse;
  out[b * 2 + 1] = z1 - m - lse;
#pragma unroll
  for (int k = 0; k < 16; ++k) out[2 * NB + b * 16 + k] = feat[k];
}

extern "C" void kernel_launch(void* const* d_in, const int* in_sizes, int n_in,
                              void* d_out, int out_size, void* d_ws,
                              size_t ws_size, hipStream_t stream) {
  (void)in_sizes;
  (void)n_in;
  (void)out_size;
  (void)d_ws;
  (void)ws_size;
  const float* x = (const float*)d_in[0];
  const float* w1 = (const float*)d_in[1];
  const float* w2 = (const float*)d_in[2];
  const float* w3 = (const float*)d_in[3];
  const float* fcw = (const float*)d_in[4];
  float* out = (float*)d_out;

  spd_stage1<<<(NB + 5) / 6, 128, 0, stream>>>(x, w1, w2);
  spd_stage2<<<NB / 8, 128, 0, stream>>>(w3);
  spd_stage3<<<NB / 256, 256, 0, stream>>>(fcw, out);
}

// Round 11
// 394.997 us; speedup vs baseline: 1.6069x; 1.0174x over previous
//
#include <hip/hip_runtime.h>
#include <math.h>

#define NB 32768
#define EPS_REC 1e-4f

// Inter-stage staging (static device globals: graph-capture safe).
__device__ float g_x2[NB * 256];  // stage-1 output: B x 16 x 16
__device__ float g_x3[NB * 16];   // stage-2 output: B x 4 x 4

// HISTORY (do not regress):
//  R5: dual-chain ILP -> occupancy halved, +22%. R6: reg-cap spills, +60%.
//  R8: 3 sweeps FAIL (absmax 1.375); 4 sweeps minimum (plateau 0.25-0.5).
//  R9-R11: two-sided, LDS-homed rounds: 641us, FETCH 23MB, CLEAN.
//  R12-R19: one-sided with REGISTER-carried column state across the
//       pragma-unroll-1 back-edge: all variants spilled ~430/850MB scratch,
//       VGPR pinned 64, occupancy 38%. Falsified: swp[] form, SSA form,
//       waves_per_eu, LDS-pad, shell, sched_barrier, ds_bpermute.
//  R20: LDS-HOMED one-sided rounds (load own col -> gram -> rot -> store to
//       permuted slot): scratch GONE (FETCH 23.5/WRITE 32.9MB = ideal),
//       VGPR 48, VALUBusy 75%, stage1 447->236us, total 402us.
//       LESSON: on this toolchain, wave-lockstep iterative state must be
//       LDS-homed; register-carrying it across the back-edge forces
//       scratch regardless of pressure/occupancy knobs. Intra-round
//       register arrays are fine (R0/R20 both clean).
//  R21 (this): VALU-bound now (75% busy, memory at ideal). Cut redundant
//       DPP: cache gram's partner-swaps in intra-round float4s and reuse
//       them in apply (-20 DPP/round = -15% VALU). R13's cache-removal
//       rationale is obsolete (pressure was never the issue). Applied to
//       both round20L and round16L.
__device__ __forceinline__ void wsync() {
  asm volatile("" ::: "memory");
  __builtin_amdgcn_wave_barrier();
  asm volatile("" ::: "memory");
}

// Swap values between adjacent lanes (lane ^ 1) via DPP quad_perm [1,0,3,2].
// Pairs (2k,2k+1) are even-aligned so they never cross a quad. VALU-pipe op.
__device__ __forceinline__ float dpp_swap1(float x) {
  int xi = __builtin_bit_cast(int, x);
  int yi = __builtin_amdgcn_update_dpp(xi, xi, 0xB1, 0xF, 0xF, true);
  return __builtin_bit_cast(float, yi);
}

__device__ __forceinline__ float4 dpp4(float4 a) {
  float4 r;
  r.x = dpp_swap1(a.x);
  r.y = dpp_swap1(a.y);
  r.z = dpp_swap1(a.z);
  r.w = dpp_swap1(a.w);
  return r;
}

// Tournament (circle-method): content of slot s moves to permf(s); with fixed
// pairing (2k,2k+1), every pair meets exactly once per N-1 rounds.
__host__ __device__ constexpr int permf(int s, int n) {
  return s == 0 ? 0
       : s == 2 ? 1
       : (s & 1) ? (s == n - 1 ? n - 2 : s + 2)
       : s - 2;
}

// Jacobi rotation (c,s) zeroing the (p,q) off-diagonal of the 2x2 Gram
// [[app,apq],[apq,aqq]]; G = [[c,s],[-s,c]].
__device__ __forceinline__ void rot_cs(float app, float aqq, float apq,
                                       float& c, float& s) {
  float dd = 0.5f * (app - aqq);
  float q2 = apq * apq;
  float hh = dd * dd + q2 + 1e-30f;
  float h = sqrtf(hh);
  float u = fabsf(dd) + h;
  float gi = rsqrtf(u * u + q2);
  c = u * gi;
  float smag = apq * gi;
  s = (dd >= 0.f) ? -smag : smag;
}

// Gram partial over one float4 with CACHED partner chunk w (d/n 2-way split).
__device__ __forceinline__ void gram4c(float4 a, float4 w, float& d0,
                                       float& d1, float& n0, float& n1) {
  d0 += a.x * w.x;
  n0 += a.x * a.x;
  d1 += a.y * w.y;
  n1 += a.y * a.y;
  d0 += a.z * w.z;
  n0 += a.z * a.z;
  d1 += a.w * w.w;
  n1 += a.w * a.w;
}

// Rotate one float4 chunk using the cached partner chunk (no DPP here).
__device__ __forceinline__ float4 app4c(float4 a, float4 w, float c,
                                        float beta) {
  float4 r;
  r.x = fmaf(beta, w.x, c * a.x);
  r.y = fmaf(beta, w.y, c * a.y);
  r.z = fmaf(beta, w.z, c * a.z);
  r.w = fmaf(beta, w.w, c * a.w);
  return r;
}

// One one-sided round, 20 rows, LDS-homed (R20 shape) with swap caching:
// load own column, DPP-swap ONCE into w*, gram from cache, rot, rotate from
// cache, store to permuted slot. No loop-carried registers; w*/a* are
// intra-round only (dead before the back-edge).
__device__ __forceinline__ void round20L(float4* SA4g, int sub, int wcol,
                                         bool isP) {
  float4 a0 = SA4g[0 * 20 + sub];
  float4 a1 = SA4g[1 * 20 + sub];
  float4 a2 = SA4g[2 * 20 + sub];
  float4 a3 = SA4g[3 * 20 + sub];
  float4 a4 = SA4g[4 * 20 + sub];
  float4 w0 = dpp4(a0);
  float4 w1_ = dpp4(a1);
  float4 w2_ = dpp4(a2);
  float4 w3_ = dpp4(a3);
  float4 w4 = dpp4(a4);
  float d0 = 0.f, d1 = 0.f, n0 = 0.f, n1 = 0.f;
  gram4c(a0, w0, d0, d1, n0, n1);
  gram4c(a1, w1_, d0, d1, n0, n1);
  gram4c(a2, w2_, d0, d1, n0, n1);
  gram4c(a3, w3_, d0, d1, n0, n1);
  gram4c(a4, w4, d0, d1, n0, n1);
  float d = d0 + d1;
  float nOwn = n0 + n1;
  float nPrt = dpp_swap1(nOwn);
  float ne = isP ? nOwn : nPrt;  // canonical order: both pair lanes identical
  float no = isP ? nPrt : nOwn;
  float c, s;
  rot_cs(ne, no, d, c, s);
  float beta = isP ? -s : s;
  wsync();  // all own-slot reads precede any overwrite (same-wave lockstep)
  SA4g[0 * 20 + wcol] = app4c(a0, w0, c, beta);
  SA4g[1 * 20 + wcol] = app4c(a1, w1_, c, beta);
  SA4g[2 * 20 + wcol] = app4c(a2, w2_, c, beta);
  SA4g[3 * 20 + wcol] = app4c(a3, w3_, c, beta);
  SA4g[4 * 20 + wcol] = app4c(a4, w4, c, beta);
  wsync();  // stores complete before next round's loads
}

// One one-sided round, 16 rows, LDS-homed, swap-cached.
__device__ __forceinline__ void round16L(float4* SB4, int sub, int wcol,
                                         bool isP) {
  float4 b0 = SB4[0 * 16 + sub];
  float4 b1 = SB4[1 * 16 + sub];
  float4 b2 = SB4[2 * 16 + sub];
  float4 b3 = SB4[3 * 16 + sub];
  float4 w0 = dpp4(b0);
  float4 w1_ = dpp4(b1);
  float4 w2_ = dpp4(b2);
  float4 w3_ = dpp4(b3);
  float d0 = 0.f, d1 = 0.f, n0 = 0.f, n1 = 0.f;
  gram4c(b0, w0, d0, d1, n0, n1);
  gram4c(b1, w1_, d0, d1, n0, n1);
  gram4c(b2, w2_, d0, d1, n0, n1);
  gram4c(b3, w3_, d0, d1, n0, n1);
  float d = d0 + d1;
  float nOwn = n0 + n1;
  float nPrt = dpp_swap1(nOwn);
  float ne = isP ? nOwn : nPrt;
  float no = isP ? nPrt : nOwn;
  float c, s;
  rot_cs(ne, no, d, c, s);
  float beta = isP ? -s : s;
  wsync();
  SB4[0 * 16 + wcol] = app4c(b0, w0, c, beta);
  SB4[1 * 16 + wcol] = app4c(b1, w1_, c, beta);
  SB4[2 * 16 + wcol] = app4c(b2, w2_, c, beta);
  SB4[3 * 16 + wcol] = app4c(b3, w3_, c, beta);
  wsync();
}

// Stage 1: X1 = w1^T X w1 (19 padded to 20), one-sided Jacobi (LDS-homed),
// then X2 = Y^T Lamc Y with Y[j] = w2^T u_j. Final slot permutation is
// irrelevant: X2 sums over eigenpairs symmetrically. 3 matrices per wave
// (lanes 60..63 -> shared dummy slot 6), 128-thread blocks. R11 shell.
__global__ __launch_bounds__(128, 4) void spd_stage1(
    const float* __restrict__ x, const float* __restrict__ w1,
    const float* __restrict__ w2) {
  __shared__ float4 ZB[7 * 100];  // Z staging / column home / Y rows
  __shared__ float SL[7 * 20];
  int tid = threadIdx.x;
  int wid = tid >> 6;
  int lane = tid & 63;
  int gl = lane / 20;  // 0..3 (3 = idle lanes 60..63)
  int sub = lane - gl * 20;
  bool lane_ok = (gl < 3);
  int g = lane_ok ? (wid * 3 + gl) : 6;
  int b = blockIdx.x * 6 + g;
  bool valid = lane_ok && (b < NB);
  int bm = valid ? b : 0;
  float4* ZB4 = ZB + g * 100;
  float* ZBf = (float*)ZB4;
  float* SLg = SL + g * 20;

  // ---- bilinear: Z = w1^T X (col sub), then X1 col sub = (Z w1) col ----
  const float* xb = x + bm * 361;
  float cx[19];
#pragma unroll
  for (int i = 0; i < 19; ++i) cx[i] = (sub < 19) ? xb[i * 19 + sub] : 0.f;
  float z[20];
  z[19] = 0.f;
#pragma unroll
  for (int i = 0; i < 19; ++i) {
    float acc = 0.f;
#pragma unroll
    for (int r = 0; r < 19; ++r) acc += w1[r * 19 + i] * cx[r];
    z[i] = acc;
  }
#pragma unroll
  for (int t = 0; t < 5; ++t)
    ZB4[t * 20 + sub] =
        make_float4(z[4 * t], z[4 * t + 1], z[4 * t + 2], z[4 * t + 3]);
  wsync();
  float wj[19];
#pragma unroll
  for (int r = 0; r < 19; ++r) wj[r] = (sub < 19) ? w1[r * 19 + sub] : 0.f;
  float a1c[20];
#pragma unroll
  for (int i = 0; i < 20; ++i) a1c[i] = 0.f;
#pragma unroll
  for (int r = 0; r < 19; ++r) {
    float wr = wj[r];
#pragma unroll
    for (int t = 0; t < 5; ++t) {
      float4 zc = ZB4[t * 20 + r];  // Z rows 4t..4t+3, col r (broadcast)
      a1c[4 * t + 0] += zc.x * wr;
      a1c[4 * t + 1] += zc.y * wr;
      a1c[4 * t + 2] += zc.z * wr;
      a1c[4 * t + 3] += zc.w * wr;
    }
  }
  wsync();  // Z reads done; ZB becomes the column home
  // Store X1 column sub into home. Pad column 19 is exactly 0 (d=0 => s=0).
  // Dummy group 6 races -> garbage, confined to slot 6, never output.
#pragma unroll
  for (int t = 0; t < 5; ++t)
    ZB4[t * 20 + sub] = make_float4(a1c[4 * t], a1c[4 * t + 1],
                                    a1c[4 * t + 2], a1c[4 * t + 3]);
  wsync();

  const int wcol = permf(sub, 20);
  const bool isP = !(sub & 1);
#pragma unroll 1
  for (int it = 0; it < 76; ++it)  // 4 sweeps (validated minimum)
    round20L(ZB4, sub, wcol, isP);

  // Load final column; lambda_j = ||col||, u_j = col/||col||.
  float cv[20];
#pragma unroll
  for (int t = 0; t < 5; ++t) {
    float4 a = ZB4[t * 20 + sub];
    cv[4 * t + 0] = a.x;
    cv[4 * t + 1] = a.y;
    cv[4 * t + 2] = a.z;
    cv[4 * t + 3] = a.w;
  }
  float m0 = 0.f, m1 = 0.f;
#pragma unroll
  for (int i = 0; i < 20; i += 2) {
    m0 += cv[i] * cv[i];
    m1 += cv[i + 1] * cv[i + 1];
  }
  float nOwn = m0 + m1;
  float lamc = fmaxf(sqrtf(nOwn), EPS_REC);
  float nrm = nOwn + 1e-30f;
  float inv = rsqrtf(nrm);
  inv = inv * (1.5f - 0.5f * nrm * inv * inv);  // 1 NR step
  // y[k] = sum_{i<19} w2[i][k] * u_j[i]   (in-lane; w2 uniform -> scalar lds)
  float y[16];
#pragma unroll
  for (int k = 0; k < 16; ++k) y[k] = 0.f;
#pragma unroll
  for (int i = 0; i < 19; ++i) {
    float ui = cv[i];
#pragma unroll
    for (int k = 0; k < 16; ++k) y[k] += w2[i * 16 + k] * ui;
  }
#pragma unroll
  for (int k = 0; k < 16; ++k) y[k] *= inv;
  wsync();  // column home dead; reuse ZB for Y rows
  SLg[sub] = lamc;
#pragma unroll
  for (int t = 0; t < 4; ++t)
    ZB4[sub * 4 + t] =
        make_float4(y[4 * t], y[4 * t + 1], y[4 * t + 2], y[4 * t + 3]);
  wsync();
  // X2[i][sub] = sum_j lamc_j Y[j][i] Y[j][sub]  (order-independent sum)
  if (valid && sub < 16) {
    float acc[16];
#pragma unroll
    for (int i = 0; i < 16; ++i) acc[i] = 0.f;
#pragma unroll
    for (int r = 0; r < 20; ++r) {
      float pr = SLg[r] * ZBf[r * 16 + sub];
#pragma unroll
      for (int t = 0; t < 4; ++t) {
        float4 yr = ZB4[r * 4 + t];  // Y row r, cols 4t..4t+3 (broadcast)
        acc[4 * t + 0] += pr * yr.x;
        acc[4 * t + 1] += pr * yr.y;
        acc[4 * t + 2] += pr * yr.z;
        acc[4 * t + 3] += pr * yr.w;
      }
    }
    float* outb = g_x2 + b * 256;
#pragma unroll
    for (int i = 0; i < 16; ++i) outb[i * 16 + sub] = acc[i];
  }
}

// Stage 2: one-sided Jacobi on 16x16 (LDS-homed), X3 = Y3^T Lamc Y3 with
// Y3[j]=w3^T u_j. 4 matrices per wave, 128-thread blocks, all lanes active.
__global__ __launch_bounds__(128, 4) void spd_stage2(
    const float* __restrict__ w3) {
  __shared__ float4 SB[8 * 64];  // column home
  __shared__ float4 Y3L[8 * 16];
  __shared__ float SL2[8 * 16];
  int tid = threadIdx.x;
  int wid = tid >> 6;
  int lane = tid & 63;
  int gl = lane >> 4;
  int sub = lane & 15;
  int g = wid * 4 + gl;
  int b = blockIdx.x * 8 + g;
  float4* SB4 = SB + g * 64;
  float* Y3f = (float*)(Y3L + g * 16);
  float* SLg = SL2 + g * 16;

  const float* xb = g_x2 + b * 256;
  float ca[16];
#pragma unroll
  for (int i = 0; i < 16; ++i) ca[i] = xb[i * 16 + sub];
#pragma unroll
  for (int t = 0; t < 4; ++t)
    SB4[t * 16 + sub] =
        make_float4(ca[4 * t], ca[4 * t + 1], ca[4 * t + 2], ca[4 * t + 3]);
  wsync();

  const int wcol = permf(sub, 16);
  const bool isP = !(sub & 1);
#pragma unroll 1
  for (int it = 0; it < 60; ++it)  // 4 sweeps
    round16L(SB4, sub, wcol, isP);

  float cv[16];
#pragma unroll
  for (int t = 0; t < 4; ++t) {
    float4 a = SB4[t * 16 + sub];
    cv[4 * t + 0] = a.x;
    cv[4 * t + 1] = a.y;
    cv[4 * t + 2] = a.z;
    cv[4 * t + 3] = a.w;
  }
  float m0 = 0.f, m1 = 0.f;
#pragma unroll
  for (int i = 0; i < 16; i += 2) {
    m0 += cv[i] * cv[i];
    m1 += cv[i + 1] * cv[i + 1];
  }
  float nOwn = m0 + m1;
  float lamc = fmaxf(sqrtf(nOwn), EPS_REC);
  float nrm = nOwn + 1e-30f;
  float inv = rsqrtf(nrm);
  inv = inv * (1.5f - 0.5f * nrm * inv * inv);
  float y3[4] = {0.f, 0.f, 0.f, 0.f};
#pragma unroll
  for (int i = 0; i < 16; ++i) {
    float ui = cv[i];
#pragma unroll
    for (int j = 0; j < 4; ++j) y3[j] += w3[i * 4 + j] * ui;
  }
#pragma unroll
  for (int j = 0; j < 4; ++j) y3[j] *= inv;
  SLg[sub] = lamc;
  ((float4*)Y3f)[sub] = make_float4(y3[0], y3[1], y3[2], y3[3]);
  wsync();
  int ii = sub >> 2, jj = sub & 3;
  float acc = 0.f;
#pragma unroll
  for (int r = 0; r < 16; ++r)
    acc += SLg[r] * Y3f[r * 4 + ii] * Y3f[r * 4 + jj];
  g_x3[b * 16 + sub] = acc;
}

// Stage 3: per-thread 4x4 LogEig in registers, FC(16->2), log_softmax.
__global__ __launch_bounds__(256) void spd_stage3(const float* __restrict__ fcw,
                                                  float* __restrict__ out) {
  int b = blockIdx.x * 256 + threadIdx.x;
  const float* xb = g_x3 + b * 16;
  float a[4][4];
#pragma unroll
  for (int i = 0; i < 4; ++i)
#pragma unroll
    for (int j = 0; j < 4; ++j) a[i][j] = xb[i * 4 + j];
  float vv[4][4];
#pragma unroll
  for (int i = 0; i < 4; ++i)
#pragma unroll
    for (int j = 0; j < 4; ++j) vv[i][j] = (i == j) ? 1.f : 0.f;

  constexpr int P4[6] = {0, 0, 0, 1, 1, 2};
  constexpr int Q4[6] = {1, 2, 3, 2, 3, 3};
  for (int sw = 0; sw < 6; ++sw) {
#pragma unroll
    for (int e = 0; e < 6; ++e) {
      const int p = P4[e], q = Q4[e];
      float c, s;
      rot_cs(a[p][p], a[q][q], a[p][q], c, s);
#pragma unroll
      for (int j = 0; j < 4; ++j) {
        float xx = a[p][j], yy = a[q][j];
        a[p][j] = c * xx - s * yy;
        a[q][j] = s * xx + c * yy;
      }
#pragma unroll
      for (int i = 0; i < 4; ++i) {
        float xx = a[i][p], yy = a[i][q];
        a[i][p] = c * xx - s * yy;
        a[i][q] = s * xx + c * yy;
      }
#pragma unroll
      for (int i = 0; i < 4; ++i) {
        float xx = vv[i][p], yy = vv[i][q];
        vv[i][p] = c * xx - s * yy;
        vv[i][q] = s * xx + c * yy;
      }
    }
  }
  float ll[4];
#pragma unroll
  for (int r = 0; r < 4; ++r) ll[r] = logf(fmaxf(a[r][r], 1e-12f));
  float feat[16];
#pragma unroll
  for (int i = 0; i < 4; ++i)
#pragma unroll
    for (int j = 0; j < 4; ++j) {
      float acc = 0.f;
#pragma unroll
      for (int r = 0; r < 4; ++r) acc += ll[r] * vv[i][r] * vv[j][r];
      feat[i * 4 + j] = acc;
    }
  float z0 = 0.f, z1 = 0.f;
#pragma unroll
  for (int k = 0; k < 16; ++k) {
    z0 += feat[k] * fcw[2 * k + 0];
    z1 += feat[k] * fcw[2 * k + 1];
  }
  float m = fmaxf(z0, z1);
  float lse = logf(expf(z0 - m) + expf(z1 - m));
  out[b * 2 + 0] = z0 - m - lse;
  out[b * 2 + 1] = z1 - m - lse;
#pragma unroll
  for (int k = 0; k < 16; ++k) out[2 * NB + b * 16 + k] = feat[k];
}

extern "C" void kernel_launch(void* const* d_in, const int* in_sizes, int n_in,
                              void* d_out, int out_size, void* d_ws,
                              size_t ws_size, hipStream_t stream) {
  (void)in_sizes;
  (void)n_in;
  (void)out_size;
  (void)d_ws;
  (void)ws_size;
  const float* x = (const float*)d_in[0];
  const float* w1 = (const float*)d_in[1];
  const float* w2 = (const float*)d_in[2];
  const float* w3 = (const float*)d_in[3];
  const float* fcw = (const float*)d_in[4];
  float* out = (float*)d_out;

  spd_stage1<<<(NB + 5) / 6, 128, 0, stream>>>(x, w1, w2);
  spd_stage2<<<NB / 8, 128, 0, stream>>>(w3);
  spd_stage3<<<NB / 256, 256, 0, stream>>>(fcw, out);
}

// Round 12
// 393.271 us; speedup vs baseline: 1.6139x; 1.0044x over previous
//
#include <hip/hip_runtime.h>
#include <math.h>

#define NB 32768
#define EPS_REC 1e-4f

// Inter-stage staging (static device globals: graph-capture safe).
__device__ float g_x2[NB * 256];  // stage-1 output: B x 16 x 16
__device__ float g_x3[NB * 16];   // stage-2 output: B x 4 x 4

// HISTORY (do not regress):
//  R5: dual-chain ILP -> occupancy halved, +22%. R6: reg-cap spills, +60%.
//  R8: 3 sweeps FAIL (absmax 1.375); 4 sweeps minimum (plateau 0.25-0.5).
//  R12-R19: one-sided with REGISTER-carried column state across the
//       pragma-unroll-1 back-edge: ~430/850MB scratch regardless of form/
//       shell/knobs. R20: LDS-HOMED rounds -> scratch GONE (23.5/33MB =
//       ideal), VGPR 48, stage1 447->236us, total 402us.
//       LESSON 1: wave-lockstep iterative state must be LDS-homed on this
//       toolchain; register-carrying across the back-edge forces scratch.
//       Intra-round register arrays are fine.
//  R21: source-level DPP caching: FLAT (236->239us).
//       LESSON 2: dpp_swap1 is pure -> compiler already CSE'd the repeated
//       swaps in R20. Count emitted ops, not source ops.
//  R22 (this): VALU-bound (75% busy, memory ideal). Halve the FMA stream
//       with packed FP32 (v_pk_fma_f32/v_pk_mul_f32 via f32x2 +
//       __builtin_elementwise_fma): gram+apply 80 scalar slots -> 40 packed
//       slots; DPP unchanged (per-32bit-reg). Round ~112 -> ~76 slots.
//       Also rot_cs sqrtf -> hh*rsqrtf(hh) (skips IEEE v_sqrt fixup; hh >=
//       1e-30). lamc keeps sqrtf (exact-0 pad column -> rsqrt inf*0 NaN).
typedef float f32x2 __attribute__((ext_vector_type(2)));

__device__ __forceinline__ f32x2 mk2(float x, float y) {
  f32x2 r;
  r.x = x;
  r.y = y;
  return r;
}

__device__ __forceinline__ void wsync() {
  asm volatile("" ::: "memory");
  __builtin_amdgcn_wave_barrier();
  asm volatile("" ::: "memory");
}

// Swap values between adjacent lanes (lane ^ 1) via DPP quad_perm [1,0,3,2].
// Pairs (2k,2k+1) are even-aligned so they never cross a quad. VALU-pipe op.
__device__ __forceinline__ float dpp_swap1(float x) {
  int xi = __builtin_bit_cast(int, x);
  int yi = __builtin_amdgcn_update_dpp(xi, xi, 0xB1, 0xF, 0xF, true);
  return __builtin_bit_cast(float, yi);
}

// Tournament (circle-method): content of slot s moves to permf(s); with fixed
// pairing (2k,2k+1), every pair meets exactly once per N-1 rounds.
__host__ __device__ constexpr int permf(int s, int n) {
  return s == 0 ? 0
       : s == 2 ? 1
       : (s & 1) ? (s == n - 1 ? n - 2 : s + 2)
       : s - 2;
}

// Jacobi rotation (c,s) zeroing the (p,q) off-diagonal of the 2x2 Gram
// [[app,apq],[apq,aqq]]; G = [[c,s],[-s,c]].  sqrt via x*rsqrt(x) (x>=1e-30).
__device__ __forceinline__ void rot_cs(float app, float aqq, float apq,
                                       float& c, float& s) {
  float dd = 0.5f * (app - aqq);
  float q2 = apq * apq;
  float hh = dd * dd + q2 + 1e-30f;
  float h = hh * rsqrtf(hh);  // == sqrt(hh), no IEEE fixup path
  float u = fabsf(dd) + h;
  float gi = rsqrtf(u * u + q2);
  c = u * gi;
  float smag = apq * gi;
  s = (dd >= 0.f) ? -smag : smag;
}

// One one-sided round, 20 rows, LDS-homed (R20 shape), packed-f32 math:
// load own column, DPP-swap once, gram via pk-FMA, rot, apply via pk-FMA,
// store to permuted slot. All temporaries intra-round (dead at back-edge).
__device__ __forceinline__ void round20L(float4* SA4g, int sub, int wcol,
                                         bool isP) {
  f32x2 lo[5], hi[5], wl[5], wh[5];
#pragma unroll
  for (int t = 0; t < 5; ++t) {
    float4 a = SA4g[t * 20 + sub];
    lo[t] = mk2(a.x, a.y);
    hi[t] = mk2(a.z, a.w);
    wl[t] = mk2(dpp_swap1(a.x), dpp_swap1(a.y));
    wh[t] = mk2(dpp_swap1(a.z), dpp_swap1(a.w));
  }
  f32x2 d2 = mk2(0.f, 0.f), n2 = mk2(0.f, 0.f);
#pragma unroll
  for (int t = 0; t < 5; ++t) {
    d2 = __builtin_elementwise_fma(lo[t], wl[t], d2);
    n2 = __builtin_elementwise_fma(lo[t], lo[t], n2);
    d2 = __builtin_elementwise_fma(hi[t], wh[t], d2);
    n2 = __builtin_elementwise_fma(hi[t], hi[t], n2);
  }
  float d = d2.x + d2.y;
  float nOwn = n2.x + n2.y;
  float nPrt = dpp_swap1(nOwn);
  float ne = isP ? nOwn : nPrt;  // canonical order: both pair lanes identical
  float no = isP ? nPrt : nOwn;
  float c, s;
  rot_cs(ne, no, d, c, s);
  float beta = isP ? -s : s;
  f32x2 cp = mk2(c, c), bp = mk2(beta, beta);
  wsync();  // all own-slot reads precede any overwrite (same-wave lockstep)
#pragma unroll
  for (int t = 0; t < 5; ++t) {
    f32x2 rlo = __builtin_elementwise_fma(wl[t], bp, lo[t] * cp);
    f32x2 rhi = __builtin_elementwise_fma(wh[t], bp, hi[t] * cp);
    SA4g[t * 20 + wcol] = make_float4(rlo.x, rlo.y, rhi.x, rhi.y);
  }
  wsync();  // stores complete before next round's loads
}

// One one-sided round, 16 rows, LDS-homed, packed-f32 math.
__device__ __forceinline__ void round16L(float4* SB4, int sub, int wcol,
                                         bool isP) {
  f32x2 lo[4], hi[4], wl[4], wh[4];
#pragma unroll
  for (int t = 0; t < 4; ++t) {
    float4 a = SB4[t * 16 + sub];
    lo[t] = mk2(a.x, a.y);
    hi[t] = mk2(a.z, a.w);
    wl[t] = mk2(dpp_swap1(a.x), dpp_swap1(a.y));
    wh[t] = mk2(dpp_swap1(a.z), dpp_swap1(a.w));
  }
  f32x2 d2 = mk2(0.f, 0.f), n2 = mk2(0.f, 0.f);
#pragma unroll
  for (int t = 0; t < 4; ++t) {
    d2 = __builtin_elementwise_fma(lo[t], wl[t], d2);
    n2 = __builtin_elementwise_fma(lo[t], lo[t], n2);
    d2 = __builtin_elementwise_fma(hi[t], wh[t], d2);
    n2 = __builtin_elementwise_fma(hi[t], hi[t], n2);
  }
  float d = d2.x + d2.y;
  float nOwn = n2.x + n2.y;
  float nPrt = dpp_swap1(nOwn);
  float ne = isP ? nOwn : nPrt;
  float no = isP ? nPrt : nOwn;
  float c, s;
  rot_cs(ne, no, d, c, s);
  float beta = isP ? -s : s;
  f32x2 cp = mk2(c, c), bp = mk2(beta, beta);
  wsync();
#pragma unroll
  for (int t = 0; t < 4; ++t) {
    f32x2 rlo = __builtin_elementwise_fma(wl[t], bp, lo[t] * cp);
    f32x2 rhi = __builtin_elementwise_fma(wh[t], bp, hi[t] * cp);
    SB4[t * 16 + wcol] = make_float4(rlo.x, rlo.y, rhi.x, rhi.y);
  }
  wsync();
}

// Stage 1: X1 = w1^T X w1 (19 padded to 20), one-sided Jacobi (LDS-homed),
// then X2 = Y^T Lamc Y with Y[j] = w2^T u_j. Final slot permutation is
// irrelevant: X2 sums over eigenpairs symmetrically. 3 matrices per wave
// (lanes 60..63 -> shared dummy slot 6), 128-thread blocks. R11 shell.
__global__ __launch_bounds__(128, 4) void spd_stage1(
    const float* __restrict__ x, const float* __restrict__ w1,
    const float* __restrict__ w2) {
  __shared__ float4 ZB[7 * 100];  // Z staging / column home / Y rows
  __shared__ float SL[7 * 20];
  int tid = threadIdx.x;
  int wid = tid >> 6;
  int lane = tid & 63;
  int gl = lane / 20;  // 0..3 (3 = idle lanes 60..63)
  int sub = lane - gl * 20;
  bool lane_ok = (gl < 3);
  int g = lane_ok ? (wid * 3 + gl) : 6;
  int b = blockIdx.x * 6 + g;
  bool valid = lane_ok && (b < NB);
  int bm = valid ? b : 0;
  float4* ZB4 = ZB + g * 100;
  float* ZBf = (float*)ZB4;
  float* SLg = SL + g * 20;

  // ---- bilinear: Z = w1^T X (col sub), then X1 col sub = (Z w1) col ----
  const float* xb = x + bm * 361;
  float cx[19];
#pragma unroll
  for (int i = 0; i < 19; ++i) cx[i] = (sub < 19) ? xb[i * 19 + sub] : 0.f;
  float z[20];
  z[19] = 0.f;
#pragma unroll
  for (int i = 0; i < 19; ++i) {
    float acc = 0.f;
#pragma unroll
    for (int r = 0; r < 19; ++r) acc += w1[r * 19 + i] * cx[r];
    z[i] = acc;
  }
#pragma unroll
  for (int t = 0; t < 5; ++t)
    ZB4[t * 20 + sub] =
        make_float4(z[4 * t], z[4 * t + 1], z[4 * t + 2], z[4 * t + 3]);
  wsync();
  float wj[19];
#pragma unroll
  for (int r = 0; r < 19; ++r) wj[r] = (sub < 19) ? w1[r * 19 + sub] : 0.f;
  float a1c[20];
#pragma unroll
  for (int i = 0; i < 20; ++i) a1c[i] = 0.f;
#pragma unroll
  for (int r = 0; r < 19; ++r) {
    float wr = wj[r];
#pragma unroll
    for (int t = 0; t < 5; ++t) {
      float4 zc = ZB4[t * 20 + r];  // Z rows 4t..4t+3, col r (broadcast)
      a1c[4 * t + 0] += zc.x * wr;
      a1c[4 * t + 1] += zc.y * wr;
      a1c[4 * t + 2] += zc.z * wr;
      a1c[4 * t + 3] += zc.w * wr;
    }
  }
  wsync();  // Z reads done; ZB becomes the column home
  // Store X1 column sub into home. Pad column 19 is exactly 0 (d=0 => s=0).
  // Dummy group 6 races -> garbage, confined to slot 6, never output.
#pragma unroll
  for (int t = 0; t < 5; ++t)
    ZB4[t * 20 + sub] = make_float4(a1c[4 * t], a1c[4 * t + 1],
                                    a1c[4 * t + 2], a1c[4 * t + 3]);
  wsync();

  const int wcol = permf(sub, 20);
  const bool isP = !(sub & 1);
#pragma unroll 1
  for (int it = 0; it < 76; ++it)  // 4 sweeps (validated minimum)
    round20L(ZB4, sub, wcol, isP);

  // Load final column; lambda_j = ||col||, u_j = col/||col||.
  float cv[20];
#pragma unroll
  for (int t = 0; t < 5; ++t) {
    float4 a = ZB4[t * 20 + sub];
    cv[4 * t + 0] = a.x;
    cv[4 * t + 1] = a.y;
    cv[4 * t + 2] = a.z;
    cv[4 * t + 3] = a.w;
  }
  float m0 = 0.f, m1 = 0.f;
#pragma unroll
  for (int i = 0; i < 20; i += 2) {
    m0 += cv[i] * cv[i];
    m1 += cv[i + 1] * cv[i + 1];
  }
  float nOwn = m0 + m1;
  float lamc = fmaxf(sqrtf(nOwn), EPS_REC);  // keep sqrtf: pad col is exact 0
  float nrm = nOwn + 1e-30f;
  float inv = rsqrtf(nrm);
  inv = inv * (1.5f - 0.5f * nrm * inv * inv);  // 1 NR step
  // y[k] = sum_{i<19} w2[i][k] * u_j[i]   (in-lane; w2 uniform -> scalar lds)
  float y[16];
#pragma unroll
  for (int k = 0; k < 16; ++k) y[k] = 0.f;
#pragma unroll
  for (int i = 0; i < 19; ++i) {
    float ui = cv[i];
#pragma unroll
    for (int k = 0; k < 16; ++k) y[k] += w2[i * 16 + k] * ui;
  }
#pragma unroll
  for (int k = 0; k < 16; ++k) y[k] *= inv;
  wsync();  // column home dead; reuse ZB for Y rows
  SLg[sub] = lamc;
#pragma unroll
  for (int t = 0; t < 4; ++t)
    ZB4[sub * 4 + t] =
        make_float4(y[4 * t], y[4 * t + 1], y[4 * t + 2], y[4 * t + 3]);
  wsync();
  // X2[i][sub] = sum_j lamc_j Y[j][i] Y[j][sub]  (order-independent sum)
  if (valid && sub < 16) {
    float acc[16];
#pragma unroll
    for (int i = 0; i < 16; ++i) acc[i] = 0.f;
#pragma unroll
    for (int r = 0; r < 20; ++r) {
      float pr = SLg[r] * ZBf[r * 16 + sub];
#pragma unroll
      for (int t = 0; t < 4; ++t) {
        float4 yr = ZB4[r * 4 + t];  // Y row r, cols 4t..4t+3 (broadcast)
        acc[4 * t + 0] += pr * yr.x;
        acc[4 * t + 1] += pr * yr.y;
        acc[4 * t + 2] += pr * yr.z;
        acc[4 * t + 3] += pr * yr.w;
      }
    }
    float* outb = g_x2 + b * 256;
#pragma unroll
    for (int i = 0; i < 16; ++i) outb[i * 16 + sub] = acc[i];
  }
}

// Stage 2: one-sided Jacobi on 16x16 (LDS-homed), X3 = Y3^T Lamc Y3 with
// Y3[j]=w3^T u_j. 4 matrices per wave, 128-thread blocks, all lanes active.
__global__ __launch_bounds__(128, 4) void spd_stage2(
    const float* __restrict__ w3) {
  __shared__ float4 SB[8 * 64];  // column home
  __shared__ float4 Y3L[8 * 16];
  __shared__ float SL2[8 * 16];
  int tid = threadIdx.x;
  int wid = tid >> 6;
  int lane = tid & 63;
  int gl = lane >> 4;
  int sub = lane & 15;
  int g = wid * 4 + gl;
  int b = blockIdx.x * 8 + g;
  float4* SB4 = SB + g * 64;
  float* Y3f = (float*)(Y3L + g * 16);
  float* SLg = SL2 + g * 16;

  const float* xb = g_x2 + b * 256;
  float ca[16];
#pragma unroll
  for (int i = 0; i < 16; ++i) ca[i] = xb[i * 16 + sub];
#pragma unroll
  for (int t = 0; t < 4; ++t)
    SB4[t * 16 + sub] =
        make_float4(ca[4 * t], ca[4 * t + 1], ca[4 * t + 2], ca[4 * t + 3]);
  wsync();

  const int wcol = permf(sub, 16);
  const bool isP = !(sub & 1);
#pragma unroll 1
  for (int it = 0; it < 60; ++it)  // 4 sweeps
    round16L(SB4, sub, wcol, isP);

  float cv[16];
#pragma unroll
  for (int t = 0; t < 4; ++t) {
    float4 a = SB4[t * 16 + sub];
    cv[4 * t + 0] = a.x;
    cv[4 * t + 1] = a.y;
    cv[4 * t + 2] = a.z;
    cv[4 * t + 3] = a.w;
  }
  float m0 = 0.f, m1 = 0.f;
#pragma unroll
  for (int i = 0; i < 16; i += 2) {
    m0 += cv[i] * cv[i];
    m1 += cv[i + 1] * cv[i + 1];
  }
  float nOwn = m0 + m1;
  float lamc = fmaxf(sqrtf(nOwn), EPS_REC);
  float nrm = nOwn + 1e-30f;
  float inv = rsqrtf(nrm);
  inv = inv * (1.5f - 0.5f * nrm * inv * inv);
  float y3[4] = {0.f, 0.f, 0.f, 0.f};
#pragma unroll
  for (int i = 0; i < 16; ++i) {
    float ui = cv[i];
#pragma unroll
    for (int j = 0; j < 4; ++j) y3[j] += w3[i * 4 + j] * ui;
  }
#pragma unroll
  for (int j = 0; j < 4; ++j) y3[j] *= inv;
  SLg[sub] = lamc;
  ((float4*)Y3f)[sub] = make_float4(y3[0], y3[1], y3[2], y3[3]);
  wsync();
  int ii = sub >> 2, jj = sub & 3;
  float acc = 0.f;
#pragma unroll
  for (int r = 0; r < 16; ++r)
    acc += SLg[r] * Y3f[r * 4 + ii] * Y3f[r * 4 + jj];
  g_x3[b * 16 + sub] = acc;
}

// Stage 3: per-thread 4x4 LogEig in registers, FC(16->2), log_softmax.
__global__ __launch_bounds__(256) void spd_stage3(const float* __restrict__ fcw,
                                                  float* __restrict__ out) {
  int b = blockIdx.x * 256 + threadIdx.x;
  const float* xb = g_x3 + b * 16;
  float a[4][4];
#pragma unroll
  for (int i = 0; i < 4; ++i)
#pragma unroll
    for (int j = 0; j < 4; ++j) a[i][j] = xb[i * 4 + j];
  float vv[4][4];
#pragma unroll
  for (int i = 0; i < 4; ++i)
#pragma unroll
    for (int j = 0; j < 4; ++j) vv[i][j] = (i == j) ? 1.f : 0.f;

  constexpr int P4[6] = {0, 0, 0, 1, 1, 2};
  constexpr int Q4[6] = {1, 2, 3, 2, 3, 3};
  for (int sw = 0; sw < 6; ++sw) {
#pragma unroll
    for (int e = 0; e < 6; ++e) {
      const int p = P4[e], q = Q4[e];
      float c, s;
      rot_cs(a[p][p], a[q][q], a[p][q], c, s);
#pragma unroll
      for (int j = 0; j < 4; ++j) {
        float xx = a[p][j], yy = a[q][j];
        a[p][j] = c * xx - s * yy;
        a[q][j] = s * xx + c * yy;
      }
#pragma unroll
      for (int i = 0; i < 4; ++i) {
        float xx = a[i][p], yy = a[i][q];
        a[i][p] = c * xx - s * yy;
        a[i][q] = s * xx + c * yy;
      }
#pragma unroll
      for (int i = 0; i < 4; ++i) {
        float xx = vv[i][p], yy = vv[i][q];
        vv[i][p] = c * xx - s * yy;
        vv[i][q] = s * xx + c * yy;
      }
    }
  }
  float ll[4];
#pragma unroll
  for (int r = 0; r < 4; ++r) ll[r] = logf(fmaxf(a[r][r], 1e-12f));
  float feat[16];
#pragma unroll
  for (int i = 0; i < 4; ++i)
#pragma unroll
    for (int j = 0; j < 4; ++j) {
      float acc = 0.f;
#pragma unroll
      for (int r = 0; r < 4; ++r) acc += ll[r] * vv[i][r] * vv[j][r];
      feat[i * 4 + j] = acc;
    }
  float z0 = 0.f, z1 = 0.f;
#pragma unroll
  for (int k = 0; k < 16; ++k) {
    z0 += feat[k] * fcw[2 * k + 0];
    z1 += feat[k] * fcw[2 * k + 1];
  }
  float m = fmaxf(z0, z1);
  float lse = logf(expf(z0 - m) + expf(z1 - m));
  out[b * 2 + 0] = z0 - m - lse;
  out[b * 2 + 1] = z1 - m - lse;
#pragma unroll
  for (int k = 0; k < 16; ++k) out[2 * NB + b * 16 + k] = feat[k];
}

extern "C" void kernel_launch(void* const* d_in, const int* in_sizes, int n_in,
                              void* d_out, int out_size, void* d_ws,
                              size_t ws_size, hipStream_t stream) {
  (void)in_sizes;
  (void)n_in;
  (void)out_size;
  (void)d_ws;
  (void)ws_size;
  const float* x = (const float*)d_in[0];
  const float* w1 = (const float*)d_in[1];
  const float* w2 = (const float*)d_in[2];
  const float* w3 = (const float*)d_in[3];
  const float* fcw = (const float*)d_in[4];
  float* out = (float*)d_out;

  spd_stage1<<<(NB + 5) / 6, 128, 0, stream>>>(x, w1, w2);
  spd_stage2<<<NB / 8, 128, 0, stream>>>(w3);
  spd_stage3<<<NB / 256, 256, 0, stream>>>(fcw, out);
}

// Round 15
// 389.351 us; speedup vs baseline: 1.6302x; 1.0101x over previous
//
#include <hip/hip_runtime.h>
#include <math.h>

#define NB 32768
#define EPS_REC 1e-4f
#define GSTRIDE 102   // stage-1 group stride in float4s (bank-balancing pad)
#define DUMMYBASE 611 // dummy group base (float4s); 611 mod 8 = 3, collides
                      // with no real group residue in either wave

// Inter-stage staging (static device globals: graph-capture safe).
__device__ float g_x2[NB * 256];  // stage-1 output: B x 16 x 16
__device__ float g_x3[NB * 16];   // stage-2 output: B x 4 x 4

// HISTORY (do not regress):
//  R5: dual-chain ILP -> occupancy halved, +22%. R6: reg-cap spills, +60%.
//  R8: 3 sweeps FAIL (absmax 1.375); 4 sweeps minimum (plateau 0.25-0.5).
//  R12-R19: register-carried column state across the pragma-unroll-1
//       back-edge -> ~430/850MB scratch regardless of form/shell/knobs.
//  R20: LDS-HOMED rounds -> scratch GONE (23.5/33MB ideal), VGPR 48,
//       stage1 447->236us, total 402us. LESSON 1: wave-lockstep iterative
//       state must be LDS-homed; intra-round register arrays are fine.
//  R21: source-level DPP caching: FLAT. LESSON 2: dpp_swap1 is pure ->
//       compiler already CSE'd. Count emitted ops, not source ops.
//  R22: packed f32 (pk_fma) + rsqrt-based rot: stage1 239->225us, total
//       393us, VGPR 48. Attribution: stage1 LDS pipe ~85% busy (162us
//       structural b128 + ~30us conflicts) vs VALU ~150us -> LDS binds.
//  R23/R24: stride 100->102 + exec-masked (if lane_ok) round loop:
//       CONTAINER FAILED TWICE (no data). Only novel construct was the
//       exec-masked loop around wave_barrier/inline-asm -> suspected
//       compile hang. LESSON 3: never resubmit identical source after two
//       container failures; differentiate to isolate infra vs kernel.
//  R25 (this): same bank theory, zero control-flow novelty vs R22:
//       stride 100->102 (wave0 residues 0/6/4) + dummy group moved to
//       base 611 (res 3; collides with nothing in either wave). Dummy
//       lanes run the loop exactly as in R22 (proven-safe shape).
typedef float f32x2 __attribute__((ext_vector_type(2)));

__device__ __forceinline__ f32x2 mk2(float x, float y) {
  f32x2 r;
  r.x = x;
  r.y = y;
  return r;
}

__device__ __forceinline__ void wsync() {
  asm volatile("" ::: "memory");
  __builtin_amdgcn_wave_barrier();
  asm volatile("" ::: "memory");
}

// Swap values between adjacent lanes (lane ^ 1) via DPP quad_perm [1,0,3,2].
// Pairs (2k,2k+1) are even-aligned so they never cross a quad. VALU-pipe op.
__device__ __forceinline__ float dpp_swap1(float x) {
  int xi = __builtin_bit_cast(int, x);
  int yi = __builtin_amdgcn_update_dpp(xi, xi, 0xB1, 0xF, 0xF, true);
  return __builtin_bit_cast(float, yi);
}

// Tournament (circle-method): content of slot s moves to permf(s); with fixed
// pairing (2k,2k+1), every pair meets exactly once per N-1 rounds.
__host__ __device__ constexpr int permf(int s, int n) {
  return s == 0 ? 0
       : s == 2 ? 1
       : (s & 1) ? (s == n - 1 ? n - 2 : s + 2)
       : s - 2;
}

// Jacobi rotation (c,s) zeroing the (p,q) off-diagonal of the 2x2 Gram
// [[app,apq],[apq,aqq]]; G = [[c,s],[-s,c]].  sqrt via x*rsqrt(x) (x>=1e-30).
__device__ __forceinline__ void rot_cs(float app, float aqq, float apq,
                                       float& c, float& s) {
  float dd = 0.5f * (app - aqq);
  float q2 = apq * apq;
  float hh = dd * dd + q2 + 1e-30f;
  float h = hh * rsqrtf(hh);  // == sqrt(hh), no IEEE fixup path
  float u = fabsf(dd) + h;
  float gi = rsqrtf(u * u + q2);
  c = u * gi;
  float smag = apq * gi;
  s = (dd >= 0.f) ? -smag : smag;
}

// One one-sided round, 20 rows, LDS-homed (R20 shape), packed-f32 math:
// load own column, DPP-swap once, gram via pk-FMA, rot, apply via pk-FMA,
// store to permuted slot. All temporaries intra-round (dead at back-edge).
__device__ __forceinline__ void round20L(float4* SA4g, int sub, int wcol,
                                         bool isP) {
  f32x2 lo[5], hi[5], wl[5], wh[5];
#pragma unroll
  for (int t = 0; t < 5; ++t) {
    float4 a = SA4g[t * 20 + sub];
    lo[t] = mk2(a.x, a.y);
    hi[t] = mk2(a.z, a.w);
    wl[t] = mk2(dpp_swap1(a.x), dpp_swap1(a.y));
    wh[t] = mk2(dpp_swap1(a.z), dpp_swap1(a.w));
  }
  f32x2 d2 = mk2(0.f, 0.f), n2 = mk2(0.f, 0.f);
#pragma unroll
  for (int t = 0; t < 5; ++t) {
    d2 = __builtin_elementwise_fma(lo[t], wl[t], d2);
    n2 = __builtin_elementwise_fma(lo[t], lo[t], n2);
    d2 = __builtin_elementwise_fma(hi[t], wh[t], d2);
    n2 = __builtin_elementwise_fma(hi[t], hi[t], n2);
  }
  float d = d2.x + d2.y;
  float nOwn = n2.x + n2.y;
  float nPrt = dpp_swap1(nOwn);
  float ne = isP ? nOwn : nPrt;  // canonical order: both pair lanes identical
  float no = isP ? nPrt : nOwn;
  float c, s;
  rot_cs(ne, no, d, c, s);
  float beta = isP ? -s : s;
  f32x2 cp = mk2(c, c), bp = mk2(beta, beta);
  wsync();  // all own-slot reads precede any overwrite (same-wave lockstep)
#pragma unroll
  for (int t = 0; t < 5; ++t) {
    f32x2 rlo = __builtin_elementwise_fma(wl[t], bp, lo[t] * cp);
    f32x2 rhi = __builtin_elementwise_fma(wh[t], bp, hi[t] * cp);
    SA4g[t * 20 + wcol] = make_float4(rlo.x, rlo.y, rhi.x, rhi.y);
  }
  wsync();  // stores complete before next round's loads
}

// One one-sided round, 16 rows, LDS-homed, packed-f32 math.
__device__ __forceinline__ void round16L(float4* SB4, int sub, int wcol,
                                         bool isP) {
  f32x2 lo[4], hi[4], wl[4], wh[4];
#pragma unroll
  for (int t = 0; t < 4; ++t) {
    float4 a = SB4[t * 16 + sub];
    lo[t] = mk2(a.x, a.y);
    hi[t] = mk2(a.z, a.w);
    wl[t] = mk2(dpp_swap1(a.x), dpp_swap1(a.y));
    wh[t] = mk2(dpp_swap1(a.z), dpp_swap1(a.w));
  }
  f32x2 d2 = mk2(0.f, 0.f), n2 = mk2(0.f, 0.f);
#pragma unroll
  for (int t = 0; t < 4; ++t) {
    d2 = __builtin_elementwise_fma(lo[t], wl[t], d2);
    n2 = __builtin_elementwise_fma(lo[t], lo[t], n2);
    d2 = __builtin_elementwise_fma(hi[t], wh[t], d2);
    n2 = __builtin_elementwise_fma(hi[t], hi[t], n2);
  }
  float d = d2.x + d2.y;
  float nOwn = n2.x + n2.y;
  float nPrt = dpp_swap1(nOwn);
  float ne = isP ? nOwn : nPrt;
  float no = isP ? nPrt : nOwn;
  float c, s;
  rot_cs(ne, no, d, c, s);
  float beta = isP ? -s : s;
  f32x2 cp = mk2(c, c), bp = mk2(beta, beta);
  wsync();
#pragma unroll
  for (int t = 0; t < 4; ++t) {
    f32x2 rlo = __builtin_elementwise_fma(wl[t], bp, lo[t] * cp);
    f32x2 rhi = __builtin_elementwise_fma(wh[t], bp, hi[t] * cp);
    SB4[t * 16 + wcol] = make_float4(rlo.x, rlo.y, rhi.x, rhi.y);
  }
  wsync();
}

// Stage 1: X1 = w1^T X w1 (19 padded to 20), one-sided Jacobi (LDS-homed),
// then X2 = Y^T Lamc Y with Y[j] = w2^T u_j. Final slot permutation is
// irrelevant: X2 sums over eigenpairs symmetrically. 3 matrices per wave
// (lanes 60..63 -> shared dummy group at DUMMYBASE), 128-thr blocks.
__global__ __launch_bounds__(128, 4) void spd_stage1(
    const float* __restrict__ x, const float* __restrict__ w1,
    const float* __restrict__ w2) {
  __shared__ float4 ZB[DUMMYBASE + 100];  // groups 0-5 at stride 102 + dummy
  __shared__ float SL[7 * 20];
  int tid = threadIdx.x;
  int wid = tid >> 6;
  int lane = tid & 63;
  int gl = lane / 20;  // 0..3 (3 = idle lanes 60..63)
  int sub = lane - gl * 20;
  bool lane_ok = (gl < 3);
  int g = lane_ok ? (wid * 3 + gl) : 6;
  int b = blockIdx.x * 6 + g;
  bool valid = lane_ok && (b < NB);
  int bm = valid ? b : 0;
  int gbase = lane_ok ? g * GSTRIDE : DUMMYBASE;
  float4* ZB4 = ZB + gbase;
  float* ZBf = (float*)ZB4;
  float* SLg = SL + g * 20;

  // ---- bilinear: Z = w1^T X (col sub), then X1 col sub = (Z w1) col ----
  const float* xb = x + bm * 361;
  float cx[19];
#pragma unroll
  for (int i = 0; i < 19; ++i) cx[i] = (sub < 19) ? xb[i * 19 + sub] : 0.f;
  float z[20];
  z[19] = 0.f;
#pragma unroll
  for (int i = 0; i < 19; ++i) {
    float acc = 0.f;
#pragma unroll
    for (int r = 0; r < 19; ++r) acc += w1[r * 19 + i] * cx[r];
    z[i] = acc;
  }
#pragma unroll
  for (int t = 0; t < 5; ++t)
    ZB4[t * 20 + sub] =
        make_float4(z[4 * t], z[4 * t + 1], z[4 * t + 2], z[4 * t + 3]);
  wsync();
  float wj[19];
#pragma unroll
  for (int r = 0; r < 19; ++r) wj[r] = (sub < 19) ? w1[r * 19 + sub] : 0.f;
  float a1c[20];
#pragma unroll
  for (int i = 0; i < 20; ++i) a1c[i] = 0.f;
#pragma unroll
  for (int r = 0; r < 19; ++r) {
    float wr = wj[r];
#pragma unroll
    for (int t = 0; t < 5; ++t) {
      float4 zc = ZB4[t * 20 + r];  // Z rows 4t..4t+3, col r (broadcast)
      a1c[4 * t + 0] += zc.x * wr;
      a1c[4 * t + 1] += zc.y * wr;
      a1c[4 * t + 2] += zc.z * wr;
      a1c[4 * t + 3] += zc.w * wr;
    }
  }
  wsync();  // Z reads done; ZB becomes the column home
  // Store X1 column sub into home. Pad column 19 is exactly 0 (d=0 => s=0).
  // Dummy group races -> garbage, confined to the dummy slots, never output.
#pragma unroll
  for (int t = 0; t < 5; ++t)
    ZB4[t * 20 + sub] = make_float4(a1c[4 * t], a1c[4 * t + 1],
                                    a1c[4 * t + 2], a1c[4 * t + 3]);
  wsync();

  const int wcol = permf(sub, 20);
  const bool isP = !(sub & 1);
#pragma unroll 1
  for (int it = 0; it < 76; ++it)  // 4 sweeps (validated minimum)
    round20L(ZB4, sub, wcol, isP);

  // Load final column; lambda_j = ||col||, u_j = col/||col||.
  float cv[20];
#pragma unroll
  for (int t = 0; t < 5; ++t) {
    float4 a = ZB4[t * 20 + sub];
    cv[4 * t + 0] = a.x;
    cv[4 * t + 1] = a.y;
    cv[4 * t + 2] = a.z;
    cv[4 * t + 3] = a.w;
  }
  float m0 = 0.f, m1 = 0.f;
#pragma unroll
  for (int i = 0; i < 20; i += 2) {
    m0 += cv[i] * cv[i];
    m1 += cv[i + 1] * cv[i + 1];
  }
  float nOwn = m0 + m1;
  float lamc = fmaxf(sqrtf(nOwn), EPS_REC);  // keep sqrtf: pad col is exact 0
  float nrm = nOwn + 1e-30f;
  float inv = rsqrtf(nrm);
  inv = inv * (1.5f - 0.5f * nrm * inv * inv);  // 1 NR step
  // y[k] = sum_{i<19} w2[i][k] * u_j[i]   (in-lane; w2 uniform -> scalar lds)
  float y[16];
#pragma unroll
  for (int k = 0; k < 16; ++k) y[k] = 0.f;
#pragma unroll
  for (int i = 0; i < 19; ++i) {
    float ui = cv[i];
#pragma unroll
    for (int k = 0; k < 16; ++k) y[k] += w2[i * 16 + k] * ui;
  }
#pragma unroll
  for (int k = 0; k < 16; ++k) y[k] *= inv;
  wsync();  // column home dead; reuse ZB for Y rows
  SLg[sub] = lamc;
#pragma unroll
  for (int t = 0; t < 4; ++t)
    ZB4[sub * 4 + t] =
        make_float4(y[4 * t], y[4 * t + 1], y[4 * t + 2], y[4 * t + 3]);
  wsync();
  // X2[i][sub] = sum_j lamc_j Y[j][i] Y[j][sub]  (order-independent sum)
  if (valid && sub < 16) {
    float acc[16];
#pragma unroll
    for (int i = 0; i < 16; ++i) acc[i] = 0.f;
#pragma unroll
    for (int r = 0; r < 20; ++r) {
      float pr = SLg[r] * ZBf[r * 16 + sub];
#pragma unroll
      for (int t = 0; t < 4; ++t) {
        float4 yr = ZB4[r * 4 + t];  // Y row r, cols 4t..4t+3 (broadcast)
        acc[4 * t + 0] += pr * yr.x;
        acc[4 * t + 1] += pr * yr.y;
        acc[4 * t + 2] += pr * yr.z;
        acc[4 * t + 3] += pr * yr.w;
      }
    }
    float* outb = g_x2 + b * 256;
#pragma unroll
    for (int i = 0; i < 16; ++i) outb[i * 16 + sub] = acc[i];
  }
}

// Stage 2: one-sided Jacobi on 16x16 (LDS-homed), X3 = Y3^T Lamc Y3 with
// Y3[j]=w3^T u_j. 4 matrices per wave, 128-thread blocks, all lanes active.
// Bank-residue analysis: stride 64 (=0 mod 8), 16-lane groups -> balanced.
__global__ __launch_bounds__(128, 4) void spd_stage2(
    const float* __restrict__ w3) {
  __shared__ float4 SB[8 * 64];  // column home
  __shared__ float4 Y3L[8 * 16];
  __shared__ float SL2[8 * 16];
  int tid = threadIdx.x;
  int wid = tid >> 6;
  int lane = tid & 63;
  int gl = lane >> 4;
  int sub = lane & 15;
  int g = wid * 4 + gl;
  int b = blockIdx.x * 8 + g;
  float4* SB4 = SB + g * 64;
  float* Y3f = (float*)(Y3L + g * 16);
  float* SLg = SL2 + g * 16;

  const float* xb = g_x2 + b * 256;
  float ca[16];
#pragma unroll
  for (int i = 0; i < 16; ++i) ca[i] = xb[i * 16 + sub];
#pragma unroll
  for (int t = 0; t < 4; ++t)
    SB4[t * 16 + sub] =
        make_float4(ca[4 * t], ca[4 * t + 1], ca[4 * t + 2], ca[4 * t + 3]);
  wsync();

  const int wcol = permf(sub, 16);
  const bool isP = !(sub & 1);
#pragma unroll 1
  for (int it = 0; it < 60; ++it)  // 4 sweeps
    round16L(SB4, sub, wcol, isP);

  float cv[16];
#pragma unroll
  for (int t = 0; t < 4; ++t) {
    float4 a = SB4[t * 16 + sub];
    cv[4 * t + 0] = a.x;
    cv[4 * t + 1] = a.y;
    cv[4 * t + 2] = a.z;
    cv[4 * t + 3] = a.w;
  }
  float m0 = 0.f, m1 = 0.f;
#pragma unroll
  for (int i = 0; i < 16; i += 2) {
    m0 += cv[i] * cv[i];
    m1 += cv[i + 1] * cv[i + 1];
  }
  float nOwn = m0 + m1;
  float lamc = fmaxf(sqrtf(nOwn), EPS_REC);
  float nrm = nOwn + 1e-30f;
  float inv = rsqrtf(nrm);
  inv = inv * (1.5f - 0.5f * nrm * inv * inv);
  float y3[4] = {0.f, 0.f, 0.f, 0.f};
#pragma unroll
  for (int i = 0; i < 16; ++i) {
    float ui = cv[i];
#pragma unroll
    for (int j = 0; j < 4; ++j) y3[j] += w3[i * 4 + j] * ui;
  }
#pragma unroll
  for (int j = 0; j < 4; ++j) y3[j] *= inv;
  SLg[sub] = lamc;
  ((float4*)Y3f)[sub] = make_float4(y3[0], y3[1], y3[2], y3[3]);
  wsync();
  int ii = sub >> 2, jj = sub & 3;
  float acc = 0.f;
#pragma unroll
  for (int r = 0; r < 16; ++r)
    acc += SLg[r] * Y3f[r * 4 + ii] * Y3f[r * 4 + jj];
  g_x3[b * 16 + sub] = acc;
}

// Stage 3: per-thread 4x4 LogEig in registers, FC(16->2), log_softmax.
__global__ __launch_bounds__(256) void spd_stage3(const float* __restrict__ fcw,
                                                  float* __restrict__ out) {
  int b = blockIdx.x * 256 + threadIdx.x;
  const float* xb = g_x3 + b * 16;
  float a[4][4];
#pragma unroll
  for (int i = 0; i < 4; ++i)
#pragma unroll
    for (int j = 0; j < 4; ++j) a[i][j] = xb[i * 4 + j];
  float vv[4][4];
#pragma unroll
  for (int i = 0; i < 4; ++i)
#pragma unroll
    for (int j = 0; j < 4; ++j) vv[i][j] = (i == j) ? 1.f : 0.f;

  constexpr int P4[6] = {0, 0, 0, 1, 1, 2};
  constexpr int Q4[6] = {1, 2, 3, 2, 3, 3};
  for (int sw = 0; sw < 6; ++sw) {
#pragma unroll
    for (int e = 0; e < 6; ++e) {
      const int p = P4[e], q = Q4[e];
      float c, s;
      rot_cs(a[p][p], a[q][q], a[p][q], c, s);
#pragma unroll
      for (int j = 0; j < 4; ++j) {
        float xx = a[p][j], yy = a[q][j];
        a[p][j] = c * xx - s * yy;
        a[q][j] = s * xx + c * yy;
      }
#pragma unroll
      for (int i = 0; i < 4; ++i) {
        float xx = a[i][p], yy = a[i][q];
        a[i][p] = c * xx - s * yy;
        a[i][q] = s * xx + c * yy;
      }
#pragma unroll
      for (int i = 0; i < 4; ++i) {
        float xx = vv[i][p], yy = vv[i][q];
        vv[i][p] = c * xx - s * yy;
        vv[i][q] = s * xx + c * yy;
      }
    }
  }
  float ll[4];
#pragma unroll
  for (int r = 0; r < 4; ++r) ll[r] = logf(fmaxf(a[r][r], 1e-12f));
  float feat[16];
#pragma unroll
  for (int i = 0; i < 4; ++i)
#pragma unroll
    for (int j = 0; j < 4; ++j) {
      float acc = 0.f;
#pragma unroll
      for (int r = 0; r < 4; ++r) acc += ll[r] * vv[i][r] * vv[j][r];
      feat[i * 4 + j] = acc;
    }
  float z0 = 0.f, z1 = 0.f;
#pragma unroll
  for (int k = 0; k < 16; ++k) {
    z0 += feat[k] * fcw[2 * k + 0];
    z1 += feat[k] * fcw[2 * k + 1];
  }
  float m = fmaxf(z0, z1);
  float lse = logf(expf(z0 - m) + expf(z1 - m));
  out[b * 2 + 0] = z0 - m - lse;
  out[b * 2 + 1] = z1 - m - lse;
#pragma unroll
  for (int k = 0; k < 16; ++k) out[2 * NB + b * 16 + k] = feat[k];
}

extern "C" void kernel_launch(void* const* d_in, const int* in_sizes, int n_in,
                              void* d_out, int out_size, void* d_ws,
                              size_t ws_size, hipStream_t stream) {
  (void)in_sizes;
  (void)n_in;
  (void)out_size;
  (void)d_ws;
  (void)ws_size;
  const float* x = (const float*)d_in[0];
  const float* w1 = (const float*)d_in[1];
  const float* w2 = (const float*)d_in[2];
  const float* w3 = (const float*)d_in[3];
  const float* fcw = (const float*)d_in[4];
  float* out = (float*)d_out;

  spd_stage1<<<(NB + 5) / 6, 128, 0, stream>>>(x, w1, w2);
  spd_stage2<<<NB / 8, 128, 0, stream>>>(w3);
  spd_stage3<<<NB / 256, 256, 0, stream>>>(fcw, out);
}